// Round 1
// baseline (5940.945 us; speedup 1.0000x reference)
//
#include <hip/hip_runtime.h>
#include <hip/hip_bf16.h>

// Problem constants
constexpr int NN = 100000;       // nodes
constexpr int NE = 1600000;      // edges
constexpr int NG = 512;          // graphs
constexpr int IND = 384;         // in dim
constexpr int HD  = 128;         // hidden dim

// ---------------------------------------------------------------------------
// init: deg = 1 (self loop), pooled = 0, cnt = 0
__global__ __launch_bounds__(256) void k_init(float* __restrict__ deg,
                                              float* __restrict__ pooled,
                                              float* __restrict__ cnt) {
    int i = blockIdx.x * 256 + threadIdx.x;
    if (i < NN) deg[i] = 1.0f;
    if (i < NG * HD) pooled[i] = 0.0f;
    if (i < NG) cnt[i] = 0.0f;
}

// deg accumulate over dst
__global__ __launch_bounds__(256) void k_deg(const int* __restrict__ ei,
                                             float* __restrict__ deg) {
    int e = blockIdx.x * 256 + threadIdx.x;
    if (e < NE) atomicAdd(&deg[ei[NE + e]], 1.0f);
}

// dinv = rsqrt(deg)
__global__ __launch_bounds__(256) void k_rsqrt(float* __restrict__ deg) {
    int i = blockIdx.x * 256 + threadIdx.x;
    if (i < NN) deg[i] = rsqrtf(deg[i]);
}

// ---------------------------------------------------------------------------
// Tiled fp32 GEMM: C[M x 128] = A[M x K] @ W[K x 128]
// Also writes Bout[row] = dinv[row]^2 * C[row]  (self-loop init for scatter).
// If BR: A-load applies a[k] = relu(a[k] + bias[k])  (bias indexed by K dim).
// In-place safe for A == Bout (each block writes only rows it alone reads).
template <int K, bool BR>
__global__ __launch_bounds__(256) void k_gemm(const float* __restrict__ A,
                                              const float* __restrict__ W,
                                              const float* __restrict__ bias,
                                              const float* __restrict__ dinv,
                                              float* __restrict__ Cout,
                                              float* __restrict__ Bout,
                                              int M) {
    __shared__ float As[64][36];    // padded rows (144B, 16B-aligned)
    __shared__ float Ws[32][132];   // padded rows (528B, 16B-aligned)
    const int tid = threadIdx.x;
    const int tx = tid & 31;        // col group: cols 4*tx .. 4*tx+3
    const int ty = tid >> 5;        // row group: rows ty*8 .. ty*8+7
    const int m0 = blockIdx.x * 64;

    float acc[8][4];
#pragma unroll
    for (int i = 0; i < 8; ++i)
#pragma unroll
        for (int c = 0; c < 4; ++c) acc[i][c] = 0.0f;

    const int arow = tid >> 2;            // 0..63
    const int akc  = (tid & 3) * 8;       // 0,8,16,24
    int ar = m0 + arow; if (ar > M - 1) ar = M - 1;
    const float* aptr = A + (size_t)ar * K + akc;
    const int wr = tid >> 3;              // 0..31
    const int wc = (tid & 7) * 4;         // 0..28

    for (int k0 = 0; k0 < K; k0 += 32) {
        float av[8];
        *(float4*)&av[0] = *(const float4*)(aptr + k0);
        *(float4*)&av[4] = *(const float4*)(aptr + k0 + 4);
        if (BR) {
#pragma unroll
            for (int j = 0; j < 8; ++j)
                av[j] = fmaxf(av[j] + bias[k0 + akc + j], 0.0f);
        }
        *(float4*)&As[arow][akc]     = *(float4*)&av[0];
        *(float4*)&As[arow][akc + 4] = *(float4*)&av[4];
#pragma unroll
        for (int t = 0; t < 4; ++t) {
            *(float4*)&Ws[wr][wc + 32 * t] =
                *(const float4*)(W + (size_t)(k0 + wr) * HD + wc + 32 * t);
        }
        __syncthreads();
#pragma unroll
        for (int kk4 = 0; kk4 < 8; ++kk4) {
            float wv[4][4];
#pragma unroll
            for (int t = 0; t < 4; ++t)
                *(float4*)wv[t] = *(const float4*)&Ws[kk4 * 4 + t][tx * 4];
#pragma unroll
            for (int i = 0; i < 8; ++i) {
                float a4[4];
                *(float4*)a4 = *(const float4*)&As[ty * 8 + i][kk4 * 4];
#pragma unroll
                for (int t = 0; t < 4; ++t)
#pragma unroll
                    for (int c = 0; c < 4; ++c)
                        acc[i][c] = fmaf(a4[t], wv[t][c], acc[i][c]);
            }
        }
        __syncthreads();
    }

#pragma unroll
    for (int i = 0; i < 8; ++i) {
        int gr = m0 + ty * 8 + i;
        if (gr < M) {
            float4 v;
            v.x = acc[i][0]; v.y = acc[i][1]; v.z = acc[i][2]; v.w = acc[i][3];
            *(float4*)(Cout + (size_t)gr * HD + tx * 4) = v;
            float dv = dinv[gr];
            float s = dv * dv;
            float4 sv;
            sv.x = v.x * s; sv.y = v.y * s; sv.z = v.z * s; sv.w = v.w * s;
            *(float4*)(Bout + (size_t)gr * HD + tx * 4) = sv;
        }
    }
}

// ---------------------------------------------------------------------------
// edge scatter: accum[dst] += dinv[src]*dinv[dst] * h[src]
// 32 threads (half-wave) per edge, float4 per thread.
__global__ __launch_bounds__(256) void k_scatter(const int* __restrict__ ei,
                                                 const float* __restrict__ dinv,
                                                 const float* __restrict__ h,
                                                 float* __restrict__ accum) {
    int gid = blockIdx.x * 256 + threadIdx.x;
    int e = gid >> 5;
    int l4 = (gid & 31) * 4;
    if (e < NE) {
        int s = ei[e];
        int d = ei[NE + e];
        float nrm = dinv[s] * dinv[d];
        const float4 v = *(const float4*)(h + (size_t)s * HD + l4);
        float* base = accum + (size_t)d * HD + l4;
        atomicAdd(base + 0, v.x * nrm);
        atomicAdd(base + 1, v.y * nrm);
        atomicAdd(base + 2, v.z * nrm);
        atomicAdd(base + 3, v.w * nrm);
    }
}

// ---------------------------------------------------------------------------
// pool: pooled[batch[n]] += relu(acc2[n] + b2); cnt[batch[n]] += 1
__global__ __launch_bounds__(256) void k_pool(const float* __restrict__ acc2,
                                              const float* __restrict__ b2,
                                              const int* __restrict__ batch,
                                              float* __restrict__ pooled,
                                              float* __restrict__ cnt) {
    int gid = blockIdx.x * 256 + threadIdx.x;
    int n = gid >> 5;
    int l4 = (gid & 31) * 4;
    if (n < NN) {
        int g = batch[n];
        float4 v = *(const float4*)(acc2 + (size_t)n * HD + l4);
        float4 b = *(const float4*)(b2 + l4);
        float r0 = fmaxf(v.x + b.x, 0.0f);
        float r1 = fmaxf(v.y + b.y, 0.0f);
        float r2 = fmaxf(v.z + b.z, 0.0f);
        float r3 = fmaxf(v.w + b.w, 0.0f);
        float* base = pooled + (size_t)g * HD + l4;
        atomicAdd(base + 0, r0);
        atomicAdd(base + 1, r1);
        atomicAdd(base + 2, r2);
        atomicAdd(base + 3, r3);
        if (l4 == 0) atomicAdd(&cnt[g], 1.0f);
    }
}

// ---------------------------------------------------------------------------
// head: logits = (pooled/cnt) @ fc_w + fc_b; out = log_softmax(logits)
__global__ void k_head(const float* __restrict__ pooled,
                       const float* __restrict__ cnt,
                       const float* __restrict__ fcw,
                       const float* __restrict__ fcb,
                       float* __restrict__ out) {
    int g = blockIdx.x;
    int l = threadIdx.x;
    float c = fmaxf(cnt[g], 1.0f);
    float inv = 1.0f / c;
    float p0 = pooled[g * HD + l] * inv;
    float p1 = pooled[g * HD + 64 + l] * inv;
    float a0 = p0 * fcw[l * 2 + 0] + p1 * fcw[(l + 64) * 2 + 0];
    float a1 = p0 * fcw[l * 2 + 1] + p1 * fcw[(l + 64) * 2 + 1];
#pragma unroll
    for (int off = 32; off; off >>= 1) {
        a0 += __shfl_down(a0, off);
        a1 += __shfl_down(a1, off);
    }
    if (l == 0) {
        a0 += fcb[0];
        a1 += fcb[1];
        float m = fmaxf(a0, a1);
        float lse = m + logf(__expf(a0 - m) + __expf(a1 - m));
        out[g * 2 + 0] = a0 - lse;
        out[g * 2 + 1] = a1 - lse;
    }
}

// ---------------------------------------------------------------------------
extern "C" void kernel_launch(void* const* d_in, const int* in_sizes, int n_in,
                              void* d_out, int out_size, void* d_ws, size_t ws_size,
                              hipStream_t stream) {
    const float* x    = (const float*)d_in[0];
    const int*   ei   = (const int*)d_in[1];   // [2][NE]
    const int*   batch= (const int*)d_in[2];   // [NN]
    const float* W1   = (const float*)d_in[3];
    const float* b1   = (const float*)d_in[4];
    const float* W2   = (const float*)d_in[5];
    const float* b2   = (const float*)d_in[6];
    const float* fcw  = (const float*)d_in[7];
    const float* fcb  = (const float*)d_in[8];
    float* out = (float*)d_out;

    float* ws = (float*)d_ws;
    float* dinv   = ws;                          // NN (padded to 100352)
    float* bufA   = dinv + 100352;               // NN*HD
    float* bufB   = bufA + (size_t)NN * HD;      // NN*HD
    float* pooled = bufB + (size_t)NN * HD;      // NG*HD
    float* cnt    = pooled + NG * HD;            // NG

    const int nblk = (NN + 255) / 256;           // 391
    const int eblk = (NE + 255) / 256;           // 6250
    const int gblk = (NN + 63) / 64;             // 1563
    const int sblk = (NE * 32) / 256;            // 200000
    const int pblk = (NN * 32 + 255) / 256;      // 12500

    k_init<<<nblk, 256, 0, stream>>>(dinv, pooled, cnt);
    k_deg<<<eblk, 256, 0, stream>>>(ei, dinv);
    k_rsqrt<<<nblk, 256, 0, stream>>>(dinv);

    // layer 1: h1 = x@W1 -> bufA ; bufB = dinv^2 * h1 (self loop)
    k_gemm<IND, false><<<gblk, 256, 0, stream>>>(x, W1, nullptr, dinv, bufA, bufB, NN);
    k_scatter<<<sblk, 256, 0, stream>>>(ei, dinv, bufA, bufB);

    // layer 2: A = relu(bufB + b1) on load; h2 -> bufA ; bufB = dinv^2 * h2
    k_gemm<HD, true><<<gblk, 256, 0, stream>>>(bufB, W2, b1, dinv, bufA, bufB, NN);
    k_scatter<<<sblk, 256, 0, stream>>>(ei, dinv, bufA, bufB);

    // pool (+b2, relu) and head
    k_pool<<<pblk, 256, 0, stream>>>(bufB, b2, batch, pooled, cnt);
    k_head<<<NG, 64, 0, stream>>>(pooled, cnt, fcw, fcb, out);
}

// Round 2
// 930.195 us; speedup vs baseline: 6.3868x; 6.3868x over previous
//
#include <hip/hip_runtime.h>
#include <hip/hip_bf16.h>

// Problem constants
constexpr int NN = 100000;       // nodes
constexpr int NE = 1600000;      // edges
constexpr int NG = 512;          // graphs
constexpr int IND = 384;         // in dim
constexpr int HD  = 128;         // hidden dim

// ---------------------------------------------------------------------------
// zero: cnt_i = 0, pooled = 0, cnt = 0
__global__ __launch_bounds__(256) void k_zero(int* __restrict__ cnt_i,
                                              float* __restrict__ pooled,
                                              float* __restrict__ cnt) {
    int i = blockIdx.x * 256 + threadIdx.x;
    if (i < NN) cnt_i[i] = 0;
    if (i < NG * HD) pooled[i] = 0.0f;
    if (i < NG) cnt[i] = 0.0f;
}

// int histogram over dst
__global__ __launch_bounds__(256) void k_cnt(const int* __restrict__ ei,
                                             int* __restrict__ cnt_i) {
    int e = blockIdx.x * 256 + threadIdx.x;
    if (e < NE) atomicAdd(&cnt_i[ei[NE + e]], 1);
}

// block-level exclusive scan of cnt_i -> row_ptr, block totals -> partial
__global__ __launch_bounds__(256) void k_scan1(const int* __restrict__ cnt_i,
                                               int* __restrict__ row_ptr,
                                               int* __restrict__ partial) {
    __shared__ int s[256];
    int t = threadIdx.x;
    int i = blockIdx.x * 256 + t;
    int v = (i < NN) ? cnt_i[i] : 0;
    s[t] = v;
    __syncthreads();
    for (int off = 1; off < 256; off <<= 1) {
        int x = (t >= off) ? s[t - off] : 0;
        __syncthreads();
        s[t] += x;
        __syncthreads();
    }
    if (i < NN) row_ptr[i] = s[t] - v;
    if (t == 255) partial[blockIdx.x] = s[255];
}

// exclusive scan of partial (nb <= 512), in place
__global__ __launch_bounds__(512) void k_scan2(int* __restrict__ partial, int nb) {
    __shared__ int s[512];
    int t = threadIdx.x;
    int v = (t < nb) ? partial[t] : 0;
    s[t] = v;
    __syncthreads();
    for (int off = 1; off < 512; off <<= 1) {
        int x = (t >= off) ? s[t - off] : 0;
        __syncthreads();
        s[t] += x;
        __syncthreads();
    }
    if (t < nb) partial[t] = s[t] - v;
}

// add block offsets; init fill cursors; dinv = rsqrt(deg_with_selfloop)
__global__ __launch_bounds__(256) void k_scan3(int* __restrict__ row_ptr,
                                               int* __restrict__ row_fill,
                                               const int* __restrict__ cnt_i,
                                               const int* __restrict__ partial,
                                               float* __restrict__ dinv) {
    int i = blockIdx.x * 256 + threadIdx.x;
    if (i < NN) {
        int r = row_ptr[i] + partial[blockIdx.x];
        row_ptr[i] = r;
        row_fill[i] = r;
        dinv[i] = rsqrtf((float)cnt_i[i] + 1.0f);
    }
    if (i == 0) row_ptr[NN] = NE;
}

// scatter edges into CSR slots; precompute per-edge norm
__global__ __launch_bounds__(256) void k_fill(const int* __restrict__ ei,
                                              const float* __restrict__ dinv,
                                              int* __restrict__ row_fill,
                                              int* __restrict__ csr_src,
                                              float* __restrict__ csr_nrm) {
    int e = blockIdx.x * 256 + threadIdx.x;
    if (e < NE) {
        int s = ei[e];
        int d = ei[NE + e];
        int pos = atomicAdd(&row_fill[d], 1);
        csr_src[pos] = s;
        csr_nrm[pos] = dinv[s] * dinv[d];
    }
}

// ---------------------------------------------------------------------------
// Tiled fp32 GEMM: C[M x 128] = A[M x K] @ W[K x 128]
// Also writes Bout[row] = dinv[row]^2 * C[row]  (self-loop init for gather).
// If BR: A-load applies a[k] = relu(a[k] + bias[k]).
// In-place safe for A == Bout.
template <int K, bool BR>
__global__ __launch_bounds__(256) void k_gemm(const float* __restrict__ A,
                                              const float* __restrict__ W,
                                              const float* __restrict__ bias,
                                              const float* __restrict__ dinv,
                                              float* __restrict__ Cout,
                                              float* __restrict__ Bout,
                                              int M) {
    __shared__ float As[64][36];
    __shared__ float Ws[32][132];
    const int tid = threadIdx.x;
    const int tx = tid & 31;
    const int ty = tid >> 5;
    const int m0 = blockIdx.x * 64;

    float acc[8][4];
#pragma unroll
    for (int i = 0; i < 8; ++i)
#pragma unroll
        for (int c = 0; c < 4; ++c) acc[i][c] = 0.0f;

    const int arow = tid >> 2;
    const int akc  = (tid & 3) * 8;
    int ar = m0 + arow; if (ar > M - 1) ar = M - 1;
    const float* aptr = A + (size_t)ar * K + akc;
    const int wr = tid >> 3;
    const int wc = (tid & 7) * 4;

    for (int k0 = 0; k0 < K; k0 += 32) {
        float av[8];
        *(float4*)&av[0] = *(const float4*)(aptr + k0);
        *(float4*)&av[4] = *(const float4*)(aptr + k0 + 4);
        if (BR) {
#pragma unroll
            for (int j = 0; j < 8; ++j)
                av[j] = fmaxf(av[j] + bias[k0 + akc + j], 0.0f);
        }
        *(float4*)&As[arow][akc]     = *(float4*)&av[0];
        *(float4*)&As[arow][akc + 4] = *(float4*)&av[4];
#pragma unroll
        for (int t = 0; t < 4; ++t) {
            *(float4*)&Ws[wr][wc + 32 * t] =
                *(const float4*)(W + (size_t)(k0 + wr) * HD + wc + 32 * t);
        }
        __syncthreads();
#pragma unroll
        for (int kk4 = 0; kk4 < 8; ++kk4) {
            float wv[4][4];
#pragma unroll
            for (int t = 0; t < 4; ++t)
                *(float4*)wv[t] = *(const float4*)&Ws[kk4 * 4 + t][tx * 4];
#pragma unroll
            for (int i = 0; i < 8; ++i) {
                float a4[4];
                *(float4*)a4 = *(const float4*)&As[ty * 8 + i][kk4 * 4];
#pragma unroll
                for (int t = 0; t < 4; ++t)
#pragma unroll
                    for (int c = 0; c < 4; ++c)
                        acc[i][c] = fmaf(a4[t], wv[t][c], acc[i][c]);
            }
        }
        __syncthreads();
    }

#pragma unroll
    for (int i = 0; i < 8; ++i) {
        int gr = m0 + ty * 8 + i;
        if (gr < M) {
            float4 v;
            v.x = acc[i][0]; v.y = acc[i][1]; v.z = acc[i][2]; v.w = acc[i][3];
            *(float4*)(Cout + (size_t)gr * HD + tx * 4) = v;
            float dv = dinv[gr];
            float s = dv * dv;
            float4 sv;
            sv.x = v.x * s; sv.y = v.y * s; sv.z = v.z * s; sv.w = v.w * s;
            *(float4*)(Bout + (size_t)gr * HD + tx * 4) = sv;
        }
    }
}

// ---------------------------------------------------------------------------
// gather: accum[n] += sum_{e in CSR row n} nrm[e] * h[src[e]]
// 32 lanes per node, float4 per lane (128 ch). No atomics.
__global__ __launch_bounds__(256) void k_gather(const int* __restrict__ row_ptr,
                                                const int* __restrict__ csr_src,
                                                const float* __restrict__ csr_nrm,
                                                const float* __restrict__ h,
                                                float* __restrict__ accum) {
    int gid = blockIdx.x * 256 + threadIdx.x;
    int node = gid >> 5;
    int l = threadIdx.x & 31;
    if (node >= NN) return;
    int start = row_ptr[node];
    int end   = row_ptr[node + 1];
    float4 acc = *(float4*)(accum + (size_t)node * HD + l * 4);
    for (int eb = start; eb < end; eb += 32) {
        int idx = eb + l;
        int src = 0;
        float nrm = 0.0f;
        if (idx < end) { src = csr_src[idx]; nrm = csr_nrm[idx]; }
        int n = min(32, end - eb);
#pragma unroll 4
        for (int j = 0; j < n; ++j) {
            int s = __shfl(src, j, 32);
            float w = __shfl(nrm, j, 32);
            const float4 v = *(const float4*)(h + (size_t)s * HD + l * 4);
            acc.x = fmaf(w, v.x, acc.x);
            acc.y = fmaf(w, v.y, acc.y);
            acc.z = fmaf(w, v.z, acc.z);
            acc.w = fmaf(w, v.w, acc.w);
        }
    }
    *(float4*)(accum + (size_t)node * HD + l * 4) = acc;
}

// ---------------------------------------------------------------------------
// pool: pooled[batch[n]] += relu(acc2[n] + b2); cnt[batch[n]] += 1
__global__ __launch_bounds__(256) void k_pool(const float* __restrict__ acc2,
                                              const float* __restrict__ b2,
                                              const int* __restrict__ batch,
                                              float* __restrict__ pooled,
                                              float* __restrict__ cnt) {
    int gid = blockIdx.x * 256 + threadIdx.x;
    int n = gid >> 5;
    int l4 = (gid & 31) * 4;
    if (n < NN) {
        int g = batch[n];
        float4 v = *(const float4*)(acc2 + (size_t)n * HD + l4);
        float4 b = *(const float4*)(b2 + l4);
        float r0 = fmaxf(v.x + b.x, 0.0f);
        float r1 = fmaxf(v.y + b.y, 0.0f);
        float r2 = fmaxf(v.z + b.z, 0.0f);
        float r3 = fmaxf(v.w + b.w, 0.0f);
        float* base = pooled + (size_t)g * HD + l4;
        atomicAdd(base + 0, r0);
        atomicAdd(base + 1, r1);
        atomicAdd(base + 2, r2);
        atomicAdd(base + 3, r3);
        if (l4 == 0) atomicAdd(&cnt[g], 1.0f);
    }
}

// ---------------------------------------------------------------------------
// head: logits = (pooled/cnt) @ fc_w + fc_b; out = log_softmax(logits)
__global__ void k_head(const float* __restrict__ pooled,
                       const float* __restrict__ cnt,
                       const float* __restrict__ fcw,
                       const float* __restrict__ fcb,
                       float* __restrict__ out) {
    int g = blockIdx.x;
    int l = threadIdx.x;
    float c = fmaxf(cnt[g], 1.0f);
    float inv = 1.0f / c;
    float p0 = pooled[g * HD + l] * inv;
    float p1 = pooled[g * HD + 64 + l] * inv;
    float a0 = p0 * fcw[l * 2 + 0] + p1 * fcw[(l + 64) * 2 + 0];
    float a1 = p0 * fcw[l * 2 + 1] + p1 * fcw[(l + 64) * 2 + 1];
#pragma unroll
    for (int off = 32; off; off >>= 1) {
        a0 += __shfl_down(a0, off);
        a1 += __shfl_down(a1, off);
    }
    if (l == 0) {
        a0 += fcb[0];
        a1 += fcb[1];
        float m = fmaxf(a0, a1);
        float lse = m + logf(__expf(a0 - m) + __expf(a1 - m));
        out[g * 2 + 0] = a0 - lse;
        out[g * 2 + 1] = a1 - lse;
    }
}

// ---------------------------------------------------------------------------
extern "C" void kernel_launch(void* const* d_in, const int* in_sizes, int n_in,
                              void* d_out, int out_size, void* d_ws, size_t ws_size,
                              hipStream_t stream) {
    const float* x    = (const float*)d_in[0];
    const int*   ei   = (const int*)d_in[1];   // [2][NE]
    const int*   batch= (const int*)d_in[2];   // [NN]
    const float* W1   = (const float*)d_in[3];
    const float* b1   = (const float*)d_in[4];
    const float* W2   = (const float*)d_in[5];
    const float* b2   = (const float*)d_in[6];
    const float* fcw  = (const float*)d_in[7];
    const float* fcb  = (const float*)d_in[8];
    float* out = (float*)d_out;

    // workspace layout
    char* ws = (char*)d_ws;
    float* dinv    = (float*)ws;                        ws += 100352 * 4;
    float* bufA    = (float*)ws;                        ws += (size_t)NN * HD * 4;
    float* bufB    = (float*)ws;                        ws += (size_t)NN * HD * 4;
    float* pooled  = (float*)ws;                        ws += NG * HD * 4;
    float* cnt     = (float*)ws;                        ws += 512 * 4;
    int*   row_ptr = (int*)ws;                          ws += 100352 * 4;
    int*   row_fill= (int*)ws;                          ws += 100352 * 4;
    int*   cnt_i   = (int*)ws;                          ws += 100352 * 4;
    int*   partial = (int*)ws;                          ws += 512 * 4;
    int*   csr_src = (int*)ws;                          ws += (size_t)NE * 4;
    float* csr_nrm = (float*)ws;                        ws += (size_t)NE * 4;

    const int nblk = (NN + 255) / 256;           // 391
    const int eblk = (NE + 255) / 256;           // 6250
    const int gblk = (NN + 63) / 64;             // 1563
    const int wblk = (NN * 32 + 255) / 256;      // 12500

    // CSR build + normalization
    k_zero <<<nblk, 256, 0, stream>>>(cnt_i, pooled, cnt);
    k_cnt  <<<eblk, 256, 0, stream>>>(ei, cnt_i);
    k_scan1<<<nblk, 256, 0, stream>>>(cnt_i, row_ptr, partial);
    k_scan2<<<1, 512, 0, stream>>>(partial, nblk);
    k_scan3<<<nblk, 256, 0, stream>>>(row_ptr, row_fill, cnt_i, partial, dinv);
    k_fill <<<eblk, 256, 0, stream>>>(ei, dinv, row_fill, csr_src, csr_nrm);

    // layer 1: h1 = x@W1 -> bufA ; bufB = dinv^2*h1 ; gather into bufB
    k_gemm<IND, false><<<gblk, 256, 0, stream>>>(x, W1, nullptr, dinv, bufA, bufB, NN);
    k_gather<<<wblk, 256, 0, stream>>>(row_ptr, csr_src, csr_nrm, bufA, bufB);

    // layer 2: A = relu(bufB + b1) on load ; h2 -> bufA ; bufB = dinv^2*h2 ; gather
    k_gemm<HD, true><<<gblk, 256, 0, stream>>>(bufB, W2, b1, dinv, bufA, bufB, NN);
    k_gather<<<wblk, 256, 0, stream>>>(row_ptr, csr_src, csr_nrm, bufA, bufB);

    // pool (+b2, relu) and head
    k_pool<<<(NN * 32 + 255) / 256, 256, 0, stream>>>(bufB, b2, batch, pooled, cnt);
    k_head<<<NG, 64, 0, stream>>>(pooled, cnt, fcw, fcb, out);
}

// Round 3
// 635.974 us; speedup vs baseline: 9.3415x; 1.4626x over previous
//
#include <hip/hip_runtime.h>
#include <hip/hip_bf16.h>

// Problem constants
constexpr int NN = 100000;       // nodes
constexpr int NE = 1600000;      // edges
constexpr int NG = 512;          // graphs
constexpr int IND = 384;         // in dim
constexpr int HD  = 128;         // hidden dim

// ---------------------------------------------------------------------------
// zero: cnt_i = 0
__global__ __launch_bounds__(256) void k_zero(int* __restrict__ cnt_i) {
    int i = blockIdx.x * 256 + threadIdx.x;
    if (i < NN) cnt_i[i] = 0;
}

// int histogram over dst
__global__ __launch_bounds__(256) void k_cnt(const int* __restrict__ ei,
                                             int* __restrict__ cnt_i) {
    int e = blockIdx.x * 256 + threadIdx.x;
    if (e < NE) atomicAdd(&cnt_i[ei[NE + e]], 1);
}

// block-level exclusive scan of cnt_i -> row_ptr, block totals -> partial
__global__ __launch_bounds__(256) void k_scan1(const int* __restrict__ cnt_i,
                                               int* __restrict__ row_ptr,
                                               int* __restrict__ partial) {
    __shared__ int s[256];
    int t = threadIdx.x;
    int i = blockIdx.x * 256 + t;
    int v = (i < NN) ? cnt_i[i] : 0;
    s[t] = v;
    __syncthreads();
    for (int off = 1; off < 256; off <<= 1) {
        int x = (t >= off) ? s[t - off] : 0;
        __syncthreads();
        s[t] += x;
        __syncthreads();
    }
    if (i < NN) row_ptr[i] = s[t] - v;
    if (t == 255) partial[blockIdx.x] = s[255];
}

// exclusive scan of partial (nb <= 512), in place
__global__ __launch_bounds__(512) void k_scan2(int* __restrict__ partial, int nb) {
    __shared__ int s[512];
    int t = threadIdx.x;
    int v = (t < nb) ? partial[t] : 0;
    s[t] = v;
    __syncthreads();
    for (int off = 1; off < 512; off <<= 1) {
        int x = (t >= off) ? s[t - off] : 0;
        __syncthreads();
        s[t] += x;
        __syncthreads();
    }
    if (t < nb) partial[t] = s[t] - v;
}

// add block offsets; init fill cursors; dinv = rsqrt(deg_with_selfloop)
__global__ __launch_bounds__(256) void k_scan3(int* __restrict__ row_ptr,
                                               int* __restrict__ row_fill,
                                               const int* __restrict__ cnt_i,
                                               const int* __restrict__ partial,
                                               float* __restrict__ dinv) {
    int i = blockIdx.x * 256 + threadIdx.x;
    if (i < NN) {
        int r = row_ptr[i] + partial[blockIdx.x];
        row_ptr[i] = r;
        row_fill[i] = r;
        dinv[i] = rsqrtf((float)cnt_i[i] + 1.0f);
    }
    if (i == 0) row_ptr[NN] = NE;
}

// scatter edges into CSR slots; precompute per-edge norm
__global__ __launch_bounds__(256) void k_fill(const int* __restrict__ ei,
                                              const float* __restrict__ dinv,
                                              int* __restrict__ row_fill,
                                              int* __restrict__ csr_src,
                                              float* __restrict__ csr_nrm) {
    int e = blockIdx.x * 256 + threadIdx.x;
    if (e < NE) {
        int s = ei[e];
        int d = ei[NE + e];
        int pos = atomicAdd(&row_fill[d], 1);
        csr_src[pos] = s;
        csr_nrm[pos] = dinv[s] * dinv[d];
    }
}

// graph boundaries from sorted batch: gstart[g] = first node of graph g
__global__ __launch_bounds__(256) void k_gbound(const int* __restrict__ batch,
                                                int* __restrict__ gstart) {
    int i = blockIdx.x * 256 + threadIdx.x;
    if (i < NN) {
        int b = batch[i];
        int prev = (i == 0) ? -1 : batch[i - 1];
        for (int g = prev + 1; g <= b; ++g) gstart[g] = i;
        if (i == NN - 1)
            for (int g = b + 1; g <= NG; ++g) gstart[g] = NN;
    }
}

// ---------------------------------------------------------------------------
// Tiled fp32 GEMM: C[M x 128] = A[M x K] @ W[K x 128]
// Also writes Bout[row] = dinv[row]^2 * C[row]  (self-loop init for gather).
// If BR: A-load applies a[k] = relu(a[k] + bias[k]).
// In-place safe for A == Bout.
template <int K, bool BR>
__global__ __launch_bounds__(256) void k_gemm(const float* __restrict__ A,
                                              const float* __restrict__ W,
                                              const float* __restrict__ bias,
                                              const float* __restrict__ dinv,
                                              float* __restrict__ Cout,
                                              float* __restrict__ Bout,
                                              int M) {
    __shared__ float As[64][36];
    __shared__ float Ws[32][132];
    const int tid = threadIdx.x;
    const int tx = tid & 31;
    const int ty = tid >> 5;
    const int m0 = blockIdx.x * 64;

    float acc[8][4];
#pragma unroll
    for (int i = 0; i < 8; ++i)
#pragma unroll
        for (int c = 0; c < 4; ++c) acc[i][c] = 0.0f;

    const int arow = tid >> 2;
    const int akc  = (tid & 3) * 8;
    int ar = m0 + arow; if (ar > M - 1) ar = M - 1;
    const float* aptr = A + (size_t)ar * K + akc;
    const int wr = tid >> 3;
    const int wc = (tid & 7) * 4;

    for (int k0 = 0; k0 < K; k0 += 32) {
        float av[8];
        *(float4*)&av[0] = *(const float4*)(aptr + k0);
        *(float4*)&av[4] = *(const float4*)(aptr + k0 + 4);
        if (BR) {
#pragma unroll
            for (int j = 0; j < 8; ++j)
                av[j] = fmaxf(av[j] + bias[k0 + akc + j], 0.0f);
        }
        *(float4*)&As[arow][akc]     = *(float4*)&av[0];
        *(float4*)&As[arow][akc + 4] = *(float4*)&av[4];
#pragma unroll
        for (int t = 0; t < 4; ++t) {
            *(float4*)&Ws[wr][wc + 32 * t] =
                *(const float4*)(W + (size_t)(k0 + wr) * HD + wc + 32 * t);
        }
        __syncthreads();
#pragma unroll
        for (int kk4 = 0; kk4 < 8; ++kk4) {
            float wv[4][4];
#pragma unroll
            for (int t = 0; t < 4; ++t)
                *(float4*)wv[t] = *(const float4*)&Ws[kk4 * 4 + t][tx * 4];
#pragma unroll
            for (int i = 0; i < 8; ++i) {
                float a4[4];
                *(float4*)a4 = *(const float4*)&As[ty * 8 + i][kk4 * 4];
#pragma unroll
                for (int t = 0; t < 4; ++t)
#pragma unroll
                    for (int c = 0; c < 4; ++c)
                        acc[i][c] = fmaf(a4[t], wv[t][c], acc[i][c]);
            }
        }
        __syncthreads();
    }

#pragma unroll
    for (int i = 0; i < 8; ++i) {
        int gr = m0 + ty * 8 + i;
        if (gr < M) {
            float4 v;
            v.x = acc[i][0]; v.y = acc[i][1]; v.z = acc[i][2]; v.w = acc[i][3];
            *(float4*)(Cout + (size_t)gr * HD + tx * 4) = v;
            float dv = dinv[gr];
            float s = dv * dv;
            float4 sv;
            sv.x = v.x * s; sv.y = v.y * s; sv.z = v.z * s; sv.w = v.w * s;
            *(float4*)(Bout + (size_t)gr * HD + tx * 4) = sv;
        }
    }
}

// ---------------------------------------------------------------------------
// gather: accum[n] += sum_{e in CSR row n} nrm[e] * h[src[e]]
// 32 lanes per node, float4 per lane (128 ch). No atomics.
__global__ __launch_bounds__(256) void k_gather(const int* __restrict__ row_ptr,
                                                const int* __restrict__ csr_src,
                                                const float* __restrict__ csr_nrm,
                                                const float* __restrict__ h,
                                                float* __restrict__ accum) {
    int gid = blockIdx.x * 256 + threadIdx.x;
    int node = gid >> 5;
    int l = threadIdx.x & 31;
    if (node >= NN) return;
    int start = row_ptr[node];
    int end   = row_ptr[node + 1];
    float4 acc = *(float4*)(accum + (size_t)node * HD + l * 4);
    for (int eb = start; eb < end; eb += 32) {
        int idx = eb + l;
        int src = 0;
        float nrm = 0.0f;
        if (idx < end) { src = csr_src[idx]; nrm = csr_nrm[idx]; }
        int n = min(32, end - eb);
#pragma unroll 4
        for (int j = 0; j < n; ++j) {
            int s = __shfl(src, j, 32);
            float w = __shfl(nrm, j, 32);
            const float4 v = *(const float4*)(h + (size_t)s * HD + l * 4);
            acc.x = fmaf(w, v.x, acc.x);
            acc.y = fmaf(w, v.y, acc.y);
            acc.z = fmaf(w, v.z, acc.z);
            acc.w = fmaf(w, v.w, acc.w);
        }
    }
    *(float4*)(accum + (size_t)node * HD + l * 4) = acc;
}

// ---------------------------------------------------------------------------
// pool + head fused: one block per graph (sorted batch -> contiguous ranges).
// pooled[c] = mean over rows of relu(acc2[row][c] + b2[c]); then
// logits = pooled @ fc_w + fc_b; out = log_softmax(logits).
__global__ __launch_bounds__(128) void k_pool2(const float* __restrict__ acc2,
                                               const float* __restrict__ b2,
                                               const int* __restrict__ gstart,
                                               const float* __restrict__ fcw,
                                               const float* __restrict__ fcb,
                                               float* __restrict__ out) {
    int g = blockIdx.x;
    int c = threadIdx.x;            // channel 0..127
    int s = gstart[g];
    int e = gstart[g + 1];
    float bias = b2[c];
    float s0 = 0.0f, s1 = 0.0f;
    int i = s;
    for (; i + 1 < e; i += 2) {
        s0 += fmaxf(acc2[(size_t)i * HD + c] + bias, 0.0f);
        s1 += fmaxf(acc2[(size_t)(i + 1) * HD + c] + bias, 0.0f);
    }
    if (i < e) s0 += fmaxf(acc2[(size_t)i * HD + c] + bias, 0.0f);
    float sum = s0 + s1;
    float p = sum / fmaxf((float)(e - s), 1.0f);

    float a0 = p * fcw[c * 2 + 0];
    float a1 = p * fcw[c * 2 + 1];
    __shared__ float r0[2], r1[2];
#pragma unroll
    for (int off = 32; off; off >>= 1) {
        a0 += __shfl_down(a0, off, 64);
        a1 += __shfl_down(a1, off, 64);
    }
    int w = c >> 6;
    if ((c & 63) == 0) { r0[w] = a0; r1[w] = a1; }
    __syncthreads();
    if (c == 0) {
        float l0 = r0[0] + r0[1] + fcb[0];
        float l1 = r1[0] + r1[1] + fcb[1];
        float m = fmaxf(l0, l1);
        float lse = m + logf(__expf(l0 - m) + __expf(l1 - m));
        out[g * 2 + 0] = l0 - lse;
        out[g * 2 + 1] = l1 - lse;
    }
}

// ---------------------------------------------------------------------------
extern "C" void kernel_launch(void* const* d_in, const int* in_sizes, int n_in,
                              void* d_out, int out_size, void* d_ws, size_t ws_size,
                              hipStream_t stream) {
    const float* x    = (const float*)d_in[0];
    const int*   ei   = (const int*)d_in[1];   // [2][NE]
    const int*   batch= (const int*)d_in[2];   // [NN] (sorted)
    const float* W1   = (const float*)d_in[3];
    const float* b1   = (const float*)d_in[4];
    const float* W2   = (const float*)d_in[5];
    const float* b2   = (const float*)d_in[6];
    const float* fcw  = (const float*)d_in[7];
    const float* fcb  = (const float*)d_in[8];
    float* out = (float*)d_out;

    // workspace layout
    char* ws = (char*)d_ws;
    float* dinv    = (float*)ws;                        ws += 100352 * 4;
    float* bufA    = (float*)ws;                        ws += (size_t)NN * HD * 4;
    float* bufB    = (float*)ws;                        ws += (size_t)NN * HD * 4;
    int*   row_ptr = (int*)ws;                          ws += 100352 * 4;
    int*   row_fill= (int*)ws;                          ws += 100352 * 4;
    int*   cnt_i   = (int*)ws;                          ws += 100352 * 4;
    int*   partial = (int*)ws;                          ws += 512 * 4;
    int*   gstart  = (int*)ws;                          ws += 516 * 4;
    int*   csr_src = (int*)ws;                          ws += (size_t)NE * 4;
    float* csr_nrm = (float*)ws;                        ws += (size_t)NE * 4;

    const int nblk = (NN + 255) / 256;           // 391
    const int eblk = (NE + 255) / 256;           // 6250
    const int gblk = (NN + 63) / 64;             // 1563
    const int wblk = (NN * 32 + 255) / 256;      // 12500

    // CSR build + normalization + graph boundaries
    k_zero <<<nblk, 256, 0, stream>>>(cnt_i);
    k_cnt  <<<eblk, 256, 0, stream>>>(ei, cnt_i);
    k_scan1<<<nblk, 256, 0, stream>>>(cnt_i, row_ptr, partial);
    k_scan2<<<1, 512, 0, stream>>>(partial, nblk);
    k_scan3<<<nblk, 256, 0, stream>>>(row_ptr, row_fill, cnt_i, partial, dinv);
    k_fill <<<eblk, 256, 0, stream>>>(ei, dinv, row_fill, csr_src, csr_nrm);
    k_gbound<<<nblk, 256, 0, stream>>>(batch, gstart);

    // layer 1: h1 = x@W1 -> bufA ; bufB = dinv^2*h1 ; gather into bufB
    k_gemm<IND, false><<<gblk, 256, 0, stream>>>(x, W1, nullptr, dinv, bufA, bufB, NN);
    k_gather<<<wblk, 256, 0, stream>>>(row_ptr, csr_src, csr_nrm, bufA, bufB);

    // layer 2: A = relu(bufB + b1) on load ; h2 -> bufA ; bufB = dinv^2*h2 ; gather
    k_gemm<HD, true><<<gblk, 256, 0, stream>>>(bufB, W2, b1, dinv, bufA, bufB, NN);
    k_gather<<<wblk, 256, 0, stream>>>(row_ptr, csr_src, csr_nrm, bufA, bufB);

    // fused pool + head
    k_pool2<<<NG, 128, 0, stream>>>(bufB, b2, gstart, fcw, fcb, out);
}

// Round 4
// 516.987 us; speedup vs baseline: 11.4915x; 1.2302x over previous
//
#include <hip/hip_runtime.h>
#include <hip/hip_bf16.h>

// Problem constants
constexpr int NN = 100000;       // nodes
constexpr int NE = 1600000;      // edges
constexpr int NG = 512;          // graphs
constexpr int IND = 384;         // in dim
constexpr int HD  = 128;         // hidden dim

typedef short bf16x8 __attribute__((ext_vector_type(8)));
typedef float f32x4  __attribute__((ext_vector_type(4)));

__device__ __forceinline__ unsigned short f2bf(float x) {
    unsigned int u = __builtin_bit_cast(unsigned int, x);
    u = (u + 0x7FFFu + ((u >> 16) & 1u)) >> 16;   // RNE
    return (unsigned short)u;
}

// ---------------------------------------------------------------------------
// zero: cnt_i = 0
__global__ __launch_bounds__(256) void k_zero(int* __restrict__ cnt_i) {
    int i = blockIdx.x * 256 + threadIdx.x;
    if (i < NN) cnt_i[i] = 0;
}

// int histogram over dst
__global__ __launch_bounds__(256) void k_cnt(const int* __restrict__ ei,
                                             int* __restrict__ cnt_i) {
    int e = blockIdx.x * 256 + threadIdx.x;
    if (e < NE) atomicAdd(&cnt_i[ei[NE + e]], 1);
}

// block-level exclusive scan of cnt_i -> row_ptr, block totals -> partial
__global__ __launch_bounds__(256) void k_scan1(const int* __restrict__ cnt_i,
                                               int* __restrict__ row_ptr,
                                               int* __restrict__ partial) {
    __shared__ int s[256];
    int t = threadIdx.x;
    int i = blockIdx.x * 256 + t;
    int v = (i < NN) ? cnt_i[i] : 0;
    s[t] = v;
    __syncthreads();
    for (int off = 1; off < 256; off <<= 1) {
        int x = (t >= off) ? s[t - off] : 0;
        __syncthreads();
        s[t] += x;
        __syncthreads();
    }
    if (i < NN) row_ptr[i] = s[t] - v;
    if (t == 255) partial[blockIdx.x] = s[255];
}

// exclusive scan of partial (nb <= 512), in place
__global__ __launch_bounds__(512) void k_scan2(int* __restrict__ partial, int nb) {
    __shared__ int s[512];
    int t = threadIdx.x;
    int v = (t < nb) ? partial[t] : 0;
    s[t] = v;
    __syncthreads();
    for (int off = 1; off < 512; off <<= 1) {
        int x = (t >= off) ? s[t - off] : 0;
        __syncthreads();
        s[t] += x;
        __syncthreads();
    }
    if (t < nb) partial[t] = s[t] - v;
}

// add block offsets; init fill cursors; dinv = rsqrt(deg_with_selfloop)
__global__ __launch_bounds__(256) void k_scan3(int* __restrict__ row_ptr,
                                               int* __restrict__ row_fill,
                                               const int* __restrict__ cnt_i,
                                               const int* __restrict__ partial,
                                               float* __restrict__ dinv) {
    int i = blockIdx.x * 256 + threadIdx.x;
    if (i < NN) {
        int r = row_ptr[i] + partial[blockIdx.x];
        row_ptr[i] = r;
        row_fill[i] = r;
        dinv[i] = rsqrtf((float)cnt_i[i] + 1.0f);
    }
    if (i == 0) row_ptr[NN] = NE;
}

// scatter edges into CSR slots; precompute per-edge norm
__global__ __launch_bounds__(256) void k_fill(const int* __restrict__ ei,
                                              const float* __restrict__ dinv,
                                              int* __restrict__ row_fill,
                                              int* __restrict__ csr_src,
                                              float* __restrict__ csr_nrm) {
    int e = blockIdx.x * 256 + threadIdx.x;
    if (e < NE) {
        int s = ei[e];
        int d = ei[NE + e];
        int pos = atomicAdd(&row_fill[d], 1);
        csr_src[pos] = s;
        csr_nrm[pos] = dinv[s] * dinv[d];
    }
}

// graph boundaries from sorted batch: gstart[g] = first node of graph g
__global__ __launch_bounds__(256) void k_gbound(const int* __restrict__ batch,
                                                int* __restrict__ gstart) {
    int i = blockIdx.x * 256 + threadIdx.x;
    if (i < NN) {
        int b = batch[i];
        int prev = (i == 0) ? -1 : batch[i - 1];
        for (int g = prev + 1; g <= b; ++g) gstart[g] = i;
        if (i == NN - 1)
            for (int g = b + 1; g <= NG; ++g) gstart[g] = NN;
    }
}

// weight prep: W1t[n][k] = bf16(W1[k][n]), W2t[n][k] = bf16(W2[k][n])
__global__ __launch_bounds__(256) void k_wprep(const float* __restrict__ W1,
                                               const float* __restrict__ W2,
                                               unsigned short* __restrict__ W1t,
                                               unsigned short* __restrict__ W2t) {
    int id = blockIdx.x * 256 + threadIdx.x;
    if (id < 128 * IND) {
        int n = id / IND, k = id - n * IND;
        W1t[id] = f2bf(W1[(size_t)k * HD + n]);
    } else {
        int id2 = id - 128 * IND;
        int n = id2 >> 7, k = id2 & 127;
        W2t[id2] = f2bf(W2[(size_t)k * HD + n]);
    }
}

// ---------------------------------------------------------------------------
// MFMA bf16 GEMM: Cout[M x 128] = A[M x K](fp32 -> bf16) @ Wt^T (Wt is [128][K] bf16)
// If BR: A-load applies a[k] = relu(a[k] + bias[k]) before conversion.
// 128x128 tile, BK=64, 4 waves each owning a 64x64 quadrant (4x4 16x16 frags).
template <int K, bool BR>
__global__ __launch_bounds__(256) void k_gemm_mfma(const float* __restrict__ A,
                                                   const unsigned short* __restrict__ Wt,
                                                   const float* __restrict__ bias,
                                                   float* __restrict__ Cout,
                                                   int M) {
    __shared__ unsigned short As[128][72];   // rows padded: stride 144B
    __shared__ unsigned short Bs[128][72];   // Bs[n][k]
    const int tid  = threadIdx.x;
    const int lane = tid & 63;
    const int wid  = tid >> 6;
    const int wm   = (wid & 1) * 64;
    const int wn   = (wid >> 1) * 64;
    const int m0   = blockIdx.x * 128;

    f32x4 acc[4][4];
#pragma unroll
    for (int i = 0; i < 4; ++i)
#pragma unroll
        for (int j = 0; j < 4; ++j) acc[i][j] = f32x4{0.f, 0.f, 0.f, 0.f};

    const int cg = tid & 15;      // A col group (4 fp32)
    const int rb = tid >> 4;      // A row base 0..15
    const int wrow = tid >> 1;    // Wt row 0..127
    const int wh   = tid & 1;     // Wt 32-col half

    for (int k0 = 0; k0 < K; k0 += 64) {
        // stage A tile (128 x 64 fp32 -> bf16)
#pragma unroll
        for (int p = 0; p < 8; ++p) {
            int r = rb + p * 16;
            int gr = m0 + r; if (gr > M - 1) gr = M - 1;
            float4 a = *(const float4*)(A + (size_t)gr * K + k0 + cg * 4);
            if (BR) {
                float4 bv = *(const float4*)(bias + k0 + cg * 4);
                a.x = fmaxf(a.x + bv.x, 0.0f);
                a.y = fmaxf(a.y + bv.y, 0.0f);
                a.z = fmaxf(a.z + bv.z, 0.0f);
                a.w = fmaxf(a.w + bv.w, 0.0f);
            }
            uint2 pk;
            pk.x = (unsigned)f2bf(a.x) | ((unsigned)f2bf(a.y) << 16);
            pk.y = (unsigned)f2bf(a.z) | ((unsigned)f2bf(a.w) << 16);
            *(uint2*)&As[r][cg * 4] = pk;
        }
        // stage Wt tile (128 rows x 64 bf16)
        {
            const uint4* src = (const uint4*)(Wt + (size_t)wrow * K + k0 + wh * 32);
#pragma unroll
            for (int q = 0; q < 4; ++q)
                *(uint4*)&Bs[wrow][wh * 32 + q * 8] = src[q];
        }
        __syncthreads();
#pragma unroll
        for (int ks = 0; ks < 2; ++ks) {
            bf16x8 af[4], bf[4];
#pragma unroll
            for (int i = 0; i < 4; ++i)
                af[i] = *(const bf16x8*)&As[wm + i * 16 + (lane & 15)][ks * 32 + (lane >> 4) * 8];
#pragma unroll
            for (int i = 0; i < 4; ++i)
                bf[i] = *(const bf16x8*)&Bs[wn + i * 16 + (lane & 15)][ks * 32 + (lane >> 4) * 8];
#pragma unroll
            for (int mi = 0; mi < 4; ++mi)
#pragma unroll
                for (int ni = 0; ni < 4; ++ni)
                    acc[mi][ni] = __builtin_amdgcn_mfma_f32_16x16x32_bf16(
                        af[mi], bf[ni], acc[mi][ni], 0, 0, 0);
        }
        __syncthreads();
    }

    // epilogue: C/D frag layout col=lane&15, row=(lane>>4)*4+reg
#pragma unroll
    for (int mi = 0; mi < 4; ++mi) {
#pragma unroll
        for (int j = 0; j < 4; ++j) {
            int gr = m0 + wm + mi * 16 + (lane >> 4) * 4 + j;
            if (gr < M) {
#pragma unroll
                for (int ni = 0; ni < 4; ++ni) {
                    int gc = wn + ni * 16 + (lane & 15);
                    Cout[(size_t)gr * HD + gc] = acc[mi][ni][j];
                }
            }
        }
    }
}

// ---------------------------------------------------------------------------
// gather: out[n] = dinv[n]^2 * h[n] + sum_{e in CSR row n} nrm[e] * h[src[e]]
// 32 lanes per node, float4 per lane (128 ch). No atomics, out write-only.
__global__ __launch_bounds__(256) void k_gather(const int* __restrict__ row_ptr,
                                                const int* __restrict__ csr_src,
                                                const float* __restrict__ csr_nrm,
                                                const float* __restrict__ dinv,
                                                const float* __restrict__ h,
                                                float* __restrict__ outb) {
    int gid = blockIdx.x * 256 + threadIdx.x;
    int node = gid >> 5;
    int l = threadIdx.x & 31;
    if (node >= NN) return;
    int start = row_ptr[node];
    int end   = row_ptr[node + 1];
    float dv = dinv[node];
    float s2 = dv * dv;
    float4 hv = *(const float4*)(h + (size_t)node * HD + l * 4);
    float4 acc;
    acc.x = s2 * hv.x; acc.y = s2 * hv.y; acc.z = s2 * hv.z; acc.w = s2 * hv.w;
    for (int eb = start; eb < end; eb += 32) {
        int idx = eb + l;
        int src = 0;
        float nrm = 0.0f;
        if (idx < end) { src = csr_src[idx]; nrm = csr_nrm[idx]; }
        int n = min(32, end - eb);
#pragma unroll 4
        for (int j = 0; j < n; ++j) {
            int s = __shfl(src, j, 32);
            float w = __shfl(nrm, j, 32);
            const float4 v = *(const float4*)(h + (size_t)s * HD + l * 4);
            acc.x = fmaf(w, v.x, acc.x);
            acc.y = fmaf(w, v.y, acc.y);
            acc.z = fmaf(w, v.z, acc.z);
            acc.w = fmaf(w, v.w, acc.w);
        }
    }
    *(float4*)(outb + (size_t)node * HD + l * 4) = acc;
}

// ---------------------------------------------------------------------------
// pool + head fused: one block per graph (sorted batch -> contiguous ranges).
__global__ __launch_bounds__(128) void k_pool2(const float* __restrict__ acc2,
                                               const float* __restrict__ b2,
                                               const int* __restrict__ gstart,
                                               const float* __restrict__ fcw,
                                               const float* __restrict__ fcb,
                                               float* __restrict__ out) {
    int g = blockIdx.x;
    int c = threadIdx.x;            // channel 0..127
    int s = gstart[g];
    int e = gstart[g + 1];
    float bias = b2[c];
    float s0 = 0.0f, s1 = 0.0f;
    int i = s;
    for (; i + 1 < e; i += 2) {
        s0 += fmaxf(acc2[(size_t)i * HD + c] + bias, 0.0f);
        s1 += fmaxf(acc2[(size_t)(i + 1) * HD + c] + bias, 0.0f);
    }
    if (i < e) s0 += fmaxf(acc2[(size_t)i * HD + c] + bias, 0.0f);
    float sum = s0 + s1;
    float p = sum / fmaxf((float)(e - s), 1.0f);

    float a0 = p * fcw[c * 2 + 0];
    float a1 = p * fcw[c * 2 + 1];
    __shared__ float r0[2], r1[2];
#pragma unroll
    for (int off = 32; off; off >>= 1) {
        a0 += __shfl_down(a0, off, 64);
        a1 += __shfl_down(a1, off, 64);
    }
    int w = c >> 6;
    if ((c & 63) == 0) { r0[w] = a0; r1[w] = a1; }
    __syncthreads();
    if (c == 0) {
        float l0 = r0[0] + r0[1] + fcb[0];
        float l1 = r1[0] + r1[1] + fcb[1];
        float m = fmaxf(l0, l1);
        float lse = m + logf(__expf(l0 - m) + __expf(l1 - m));
        out[g * 2 + 0] = l0 - lse;
        out[g * 2 + 1] = l1 - lse;
    }
}

// ---------------------------------------------------------------------------
extern "C" void kernel_launch(void* const* d_in, const int* in_sizes, int n_in,
                              void* d_out, int out_size, void* d_ws, size_t ws_size,
                              hipStream_t stream) {
    const float* x    = (const float*)d_in[0];
    const int*   ei   = (const int*)d_in[1];   // [2][NE]
    const int*   batch= (const int*)d_in[2];   // [NN] (sorted)
    const float* W1   = (const float*)d_in[3];
    const float* b1   = (const float*)d_in[4];
    const float* W2   = (const float*)d_in[5];
    const float* b2   = (const float*)d_in[6];
    const float* fcw  = (const float*)d_in[7];
    const float* fcb  = (const float*)d_in[8];
    float* out = (float*)d_out;

    // workspace layout
    char* ws = (char*)d_ws;
    float* dinv    = (float*)ws;                        ws += 100352 * 4;
    float* bufA    = (float*)ws;                        ws += (size_t)NN * HD * 4;
    float* bufB    = (float*)ws;                        ws += (size_t)NN * HD * 4;
    int*   row_ptr = (int*)ws;                          ws += 100352 * 4;
    int*   row_fill= (int*)ws;                          ws += 100352 * 4;
    int*   cnt_i   = (int*)ws;                          ws += 100352 * 4;
    int*   partial = (int*)ws;                          ws += 512 * 4;
    int*   gstart  = (int*)ws;                          ws += 516 * 4;
    unsigned short* W1t = (unsigned short*)ws;          ws += (size_t)128 * IND * 2;
    unsigned short* W2t = (unsigned short*)ws;          ws += (size_t)128 * HD * 2;
    int*   csr_src = (int*)ws;                          ws += (size_t)NE * 4;
    float* csr_nrm = (float*)ws;                        ws += (size_t)NE * 4;

    const int nblk = (NN + 255) / 256;           // 391
    const int eblk = (NE + 255) / 256;           // 6250
    const int mblk = (NN + 127) / 128;           // 782
    const int wblk = (NN * 32 + 255) / 256;      // 12500

    // CSR build + normalization + graph boundaries + weight prep
    k_zero <<<nblk, 256, 0, stream>>>(cnt_i);
    k_cnt  <<<eblk, 256, 0, stream>>>(ei, cnt_i);
    k_scan1<<<nblk, 256, 0, stream>>>(cnt_i, row_ptr, partial);
    k_scan2<<<1, 512, 0, stream>>>(partial, nblk);
    k_scan3<<<nblk, 256, 0, stream>>>(row_ptr, row_fill, cnt_i, partial, dinv);
    k_fill <<<eblk, 256, 0, stream>>>(ei, dinv, row_fill, csr_src, csr_nrm);
    k_gbound<<<nblk, 256, 0, stream>>>(batch, gstart);
    k_wprep<<<(128 * (IND + HD)) / 256, 256, 0, stream>>>(W1, W2, W1t, W2t);

    // layer 1: h1 = x@W1 -> bufA ; gather (self-loop init) -> bufB
    k_gemm_mfma<IND, false><<<mblk, 256, 0, stream>>>(x, W1t, nullptr, bufA, NN);
    k_gather<<<wblk, 256, 0, stream>>>(row_ptr, csr_src, csr_nrm, dinv, bufA, bufB);

    // layer 2: A = relu(bufB + b1) on load ; h2 -> bufA ; gather -> bufB
    k_gemm_mfma<HD, true><<<mblk, 256, 0, stream>>>(bufB, W2t, b1, bufA, NN);
    k_gather<<<wblk, 256, 0, stream>>>(row_ptr, csr_src, csr_nrm, dinv, bufA, bufB);

    // fused pool + head
    k_pool2<<<NG, 128, 0, stream>>>(bufB, b2, gstart, fcw, fcb, out);
}

// Round 5
// 415.101 us; speedup vs baseline: 14.3120x; 1.2454x over previous
//
#include <hip/hip_runtime.h>
#include <hip/hip_bf16.h>

// Problem constants
constexpr int NN = 100000;       // nodes
constexpr int NE = 1600000;      // edges
constexpr int NG = 512;          // graphs
constexpr int IND = 384;         // in dim
constexpr int HD  = 128;         // hidden dim

typedef short bf16x8 __attribute__((ext_vector_type(8)));
typedef float f32x4  __attribute__((ext_vector_type(4)));

__device__ __forceinline__ unsigned short f2bf(float x) {
    unsigned int u = __builtin_bit_cast(unsigned int, x);
    u = (u + 0x7FFFu + ((u >> 16) & 1u)) >> 16;   // RNE
    return (unsigned short)u;
}

// ---------------------------------------------------------------------------
// zero: cnt_i = 0
__global__ __launch_bounds__(256) void k_zero(int* __restrict__ cnt_i) {
    int i = blockIdx.x * 256 + threadIdx.x;
    if (i < NN) cnt_i[i] = 0;
}

// int histogram over dst
__global__ __launch_bounds__(256) void k_cnt(const int* __restrict__ ei,
                                             int* __restrict__ cnt_i) {
    int e = blockIdx.x * 256 + threadIdx.x;
    if (e < NE) atomicAdd(&cnt_i[ei[NE + e]], 1);
}

// block-level exclusive scan of cnt_i -> row_ptr, block totals -> partial
__global__ __launch_bounds__(256) void k_scan1(const int* __restrict__ cnt_i,
                                               int* __restrict__ row_ptr,
                                               int* __restrict__ partial) {
    __shared__ int s[256];
    int t = threadIdx.x;
    int i = blockIdx.x * 256 + t;
    int v = (i < NN) ? cnt_i[i] : 0;
    s[t] = v;
    __syncthreads();
    for (int off = 1; off < 256; off <<= 1) {
        int x = (t >= off) ? s[t - off] : 0;
        __syncthreads();
        s[t] += x;
        __syncthreads();
    }
    if (i < NN) row_ptr[i] = s[t] - v;
    if (t == 255) partial[blockIdx.x] = s[255];
}

// exclusive scan of partial (nb <= 512), in place
__global__ __launch_bounds__(512) void k_scan2(int* __restrict__ partial, int nb) {
    __shared__ int s[512];
    int t = threadIdx.x;
    int v = (t < nb) ? partial[t] : 0;
    s[t] = v;
    __syncthreads();
    for (int off = 1; off < 512; off <<= 1) {
        int x = (t >= off) ? s[t - off] : 0;
        __syncthreads();
        s[t] += x;
        __syncthreads();
    }
    if (t < nb) partial[t] = s[t] - v;
}

// add block offsets; init fill cursors; dinv = rsqrt(deg_with_selfloop)
__global__ __launch_bounds__(256) void k_scan3(int* __restrict__ row_ptr,
                                               int* __restrict__ row_fill,
                                               const int* __restrict__ cnt_i,
                                               const int* __restrict__ partial,
                                               float* __restrict__ dinv) {
    int i = blockIdx.x * 256 + threadIdx.x;
    if (i < NN) {
        int r = row_ptr[i] + partial[blockIdx.x];
        row_ptr[i] = r;
        row_fill[i] = r;
        dinv[i] = rsqrtf((float)cnt_i[i] + 1.0f);
    }
    if (i == 0) row_ptr[NN] = NE;
}

// scatter edges into CSR slots; precompute per-edge norm
__global__ __launch_bounds__(256) void k_fill(const int* __restrict__ ei,
                                              const float* __restrict__ dinv,
                                              int* __restrict__ row_fill,
                                              int* __restrict__ csr_src,
                                              float* __restrict__ csr_nrm) {
    int e = blockIdx.x * 256 + threadIdx.x;
    if (e < NE) {
        int s = ei[e];
        int d = ei[NE + e];
        int pos = atomicAdd(&row_fill[d], 1);
        csr_src[pos] = s;
        csr_nrm[pos] = dinv[s] * dinv[d];
    }
}

// graph boundaries from sorted batch: gstart[g] = first node of graph g
__global__ __launch_bounds__(256) void k_gbound(const int* __restrict__ batch,
                                                int* __restrict__ gstart) {
    int i = blockIdx.x * 256 + threadIdx.x;
    if (i < NN) {
        int b = batch[i];
        int prev = (i == 0) ? -1 : batch[i - 1];
        for (int g = prev + 1; g <= b; ++g) gstart[g] = i;
        if (i == NN - 1)
            for (int g = b + 1; g <= NG; ++g) gstart[g] = NN;
    }
}

// weight prep: W1t[n][k] = bf16(W1[k][n]), W2t[n][k] = bf16(W2[k][n])
__global__ __launch_bounds__(256) void k_wprep(const float* __restrict__ W1,
                                               const float* __restrict__ W2,
                                               unsigned short* __restrict__ W1t,
                                               unsigned short* __restrict__ W2t) {
    int id = blockIdx.x * 256 + threadIdx.x;
    if (id < 128 * IND) {
        int n = id / IND, k = id - n * IND;
        W1t[id] = f2bf(W1[(size_t)k * HD + n]);
    } else {
        int id2 = id - 128 * IND;
        int n = id2 >> 7, k = id2 & 127;
        W2t[id2] = f2bf(W2[(size_t)k * HD + n]);
    }
}

// ---------------------------------------------------------------------------
// MFMA bf16 GEMM: Cout[M x 128](bf16) = A[M x K](fp32 -> bf16) @ Wt^T
// (Wt is [128][K] bf16). If BR: A applies relu(a + bias) before conversion.
// 128x128 tile, BK=64, 4 waves each owning a 64x64 quadrant (4x4 16x16 frags).
template <int K, bool BR>
__global__ __launch_bounds__(256) void k_gemm_mfma(const float* __restrict__ A,
                                                   const unsigned short* __restrict__ Wt,
                                                   const float* __restrict__ bias,
                                                   unsigned short* __restrict__ Cout,
                                                   int M) {
    __shared__ unsigned short As[128][72];   // rows padded: stride 144B
    __shared__ unsigned short Bs[128][72];   // Bs[n][k]
    const int tid  = threadIdx.x;
    const int lane = tid & 63;
    const int wid  = tid >> 6;
    const int wm   = (wid & 1) * 64;
    const int wn   = (wid >> 1) * 64;
    const int m0   = blockIdx.x * 128;

    f32x4 acc[4][4];
#pragma unroll
    for (int i = 0; i < 4; ++i)
#pragma unroll
        for (int j = 0; j < 4; ++j) acc[i][j] = f32x4{0.f, 0.f, 0.f, 0.f};

    const int cg = tid & 15;      // A col group (4 fp32)
    const int rb = tid >> 4;      // A row base 0..15
    const int wrow = tid >> 1;    // Wt row 0..127
    const int wh   = tid & 1;     // Wt 32-col half

    for (int k0 = 0; k0 < K; k0 += 64) {
        // stage A tile (128 x 64 fp32 -> bf16)
#pragma unroll
        for (int p = 0; p < 8; ++p) {
            int r = rb + p * 16;
            int gr = m0 + r; if (gr > M - 1) gr = M - 1;
            float4 a = *(const float4*)(A + (size_t)gr * K + k0 + cg * 4);
            if (BR) {
                float4 bv = *(const float4*)(bias + k0 + cg * 4);
                a.x = fmaxf(a.x + bv.x, 0.0f);
                a.y = fmaxf(a.y + bv.y, 0.0f);
                a.z = fmaxf(a.z + bv.z, 0.0f);
                a.w = fmaxf(a.w + bv.w, 0.0f);
            }
            uint2 pk;
            pk.x = (unsigned)f2bf(a.x) | ((unsigned)f2bf(a.y) << 16);
            pk.y = (unsigned)f2bf(a.z) | ((unsigned)f2bf(a.w) << 16);
            *(uint2*)&As[r][cg * 4] = pk;
        }
        // stage Wt tile (128 rows x 64 bf16)
        {
            const uint4* src = (const uint4*)(Wt + (size_t)wrow * K + k0 + wh * 32);
#pragma unroll
            for (int q = 0; q < 4; ++q)
                *(uint4*)&Bs[wrow][wh * 32 + q * 8] = src[q];
        }
        __syncthreads();
#pragma unroll
        for (int ks = 0; ks < 2; ++ks) {
            bf16x8 af[4], bfr[4];
#pragma unroll
            for (int i = 0; i < 4; ++i)
                af[i] = *(const bf16x8*)&As[wm + i * 16 + (lane & 15)][ks * 32 + (lane >> 4) * 8];
#pragma unroll
            for (int i = 0; i < 4; ++i)
                bfr[i] = *(const bf16x8*)&Bs[wn + i * 16 + (lane & 15)][ks * 32 + (lane >> 4) * 8];
#pragma unroll
            for (int mi = 0; mi < 4; ++mi)
#pragma unroll
                for (int ni = 0; ni < 4; ++ni)
                    acc[mi][ni] = __builtin_amdgcn_mfma_f32_16x16x32_bf16(
                        af[mi], bfr[ni], acc[mi][ni], 0, 0, 0);
        }
        __syncthreads();
    }

    // epilogue: C/D frag layout col=lane&15, row=(lane>>4)*4+reg; emit bf16
#pragma unroll
    for (int mi = 0; mi < 4; ++mi) {
#pragma unroll
        for (int j = 0; j < 4; ++j) {
            int gr = m0 + wm + mi * 16 + (lane >> 4) * 4 + j;
            if (gr < M) {
#pragma unroll
                for (int ni = 0; ni < 4; ++ni) {
                    int gc = wn + ni * 16 + (lane & 15);
                    Cout[(size_t)gr * HD + gc] = f2bf(acc[mi][ni][j]);
                }
            }
        }
    }
}

// ---------------------------------------------------------------------------
// gather: out[n] = dinv[n]^2 * h[n] + sum_{e in CSR row n} nrm[e] * h[src[e]]
// h is bf16 [NN][128]; 32 lanes per node, 4 channels (8B) per lane.
// fp32 accumulate, fp32 output. No atomics, out write-only.
__global__ __launch_bounds__(256) void k_gather(const int* __restrict__ row_ptr,
                                                const int* __restrict__ csr_src,
                                                const float* __restrict__ csr_nrm,
                                                const float* __restrict__ dinv,
                                                const unsigned short* __restrict__ h,
                                                float* __restrict__ outb) {
    int gid = blockIdx.x * 256 + threadIdx.x;
    int node = gid >> 5;
    int l = threadIdx.x & 31;
    if (node >= NN) return;
    int start = row_ptr[node];
    int end   = row_ptr[node + 1];
    float dv = dinv[node];
    float s2 = dv * dv;
    uint2 hp = *(const uint2*)(h + (size_t)node * HD + l * 4);
    float4 acc;
    acc.x = s2 * __builtin_bit_cast(float, hp.x << 16);
    acc.y = s2 * __builtin_bit_cast(float, hp.x & 0xffff0000u);
    acc.z = s2 * __builtin_bit_cast(float, hp.y << 16);
    acc.w = s2 * __builtin_bit_cast(float, hp.y & 0xffff0000u);
    for (int eb = start; eb < end; eb += 32) {
        int idx = eb + l;
        int src = 0;
        float nrm = 0.0f;
        if (idx < end) { src = csr_src[idx]; nrm = csr_nrm[idx]; }
        int n = min(32, end - eb);
#pragma unroll 4
        for (int j = 0; j < n; ++j) {
            int s = __shfl(src, j, 32);
            float w = __shfl(nrm, j, 32);
            uint2 pk = *(const uint2*)(h + (size_t)s * HD + l * 4);
            acc.x = fmaf(w, __builtin_bit_cast(float, pk.x << 16), acc.x);
            acc.y = fmaf(w, __builtin_bit_cast(float, pk.x & 0xffff0000u), acc.y);
            acc.z = fmaf(w, __builtin_bit_cast(float, pk.y << 16), acc.z);
            acc.w = fmaf(w, __builtin_bit_cast(float, pk.y & 0xffff0000u), acc.w);
        }
    }
    *(float4*)(outb + (size_t)node * HD + l * 4) = acc;
}

// ---------------------------------------------------------------------------
// pool + head fused: one block per graph (sorted batch -> contiguous ranges).
__global__ __launch_bounds__(128) void k_pool2(const float* __restrict__ acc2,
                                               const float* __restrict__ b2,
                                               const int* __restrict__ gstart,
                                               const float* __restrict__ fcw,
                                               const float* __restrict__ fcb,
                                               float* __restrict__ out) {
    int g = blockIdx.x;
    int c = threadIdx.x;            // channel 0..127
    int s = gstart[g];
    int e = gstart[g + 1];
    float bias = b2[c];
    float s0 = 0.0f, s1 = 0.0f;
    int i = s;
    for (; i + 1 < e; i += 2) {
        s0 += fmaxf(acc2[(size_t)i * HD + c] + bias, 0.0f);
        s1 += fmaxf(acc2[(size_t)(i + 1) * HD + c] + bias, 0.0f);
    }
    if (i < e) s0 += fmaxf(acc2[(size_t)i * HD + c] + bias, 0.0f);
    float sum = s0 + s1;
    float p = sum / fmaxf((float)(e - s), 1.0f);

    float a0 = p * fcw[c * 2 + 0];
    float a1 = p * fcw[c * 2 + 1];
    __shared__ float r0[2], r1[2];
#pragma unroll
    for (int off = 32; off; off >>= 1) {
        a0 += __shfl_down(a0, off, 64);
        a1 += __shfl_down(a1, off, 64);
    }
    int w = c >> 6;
    if ((c & 63) == 0) { r0[w] = a0; r1[w] = a1; }
    __syncthreads();
    if (c == 0) {
        float l0 = r0[0] + r0[1] + fcb[0];
        float l1 = r1[0] + r1[1] + fcb[1];
        float m = fmaxf(l0, l1);
        float lse = m + logf(__expf(l0 - m) + __expf(l1 - m));
        out[g * 2 + 0] = l0 - lse;
        out[g * 2 + 1] = l1 - lse;
    }
}

// ---------------------------------------------------------------------------
extern "C" void kernel_launch(void* const* d_in, const int* in_sizes, int n_in,
                              void* d_out, int out_size, void* d_ws, size_t ws_size,
                              hipStream_t stream) {
    const float* x    = (const float*)d_in[0];
    const int*   ei   = (const int*)d_in[1];   // [2][NE]
    const int*   batch= (const int*)d_in[2];   // [NN] (sorted)
    const float* W1   = (const float*)d_in[3];
    const float* b1   = (const float*)d_in[4];
    const float* W2   = (const float*)d_in[5];
    const float* b2   = (const float*)d_in[6];
    const float* fcw  = (const float*)d_in[7];
    const float* fcb  = (const float*)d_in[8];
    float* out = (float*)d_out;

    // workspace layout
    char* ws = (char*)d_ws;
    float* dinv    = (float*)ws;                        ws += 100352 * 4;
    unsigned short* bufA = (unsigned short*)ws;         ws += (size_t)NN * HD * 2;  // bf16 h
    float* bufB    = (float*)ws;                        ws += (size_t)NN * HD * 4;  // fp32 agg
    int*   row_ptr = (int*)ws;                          ws += 100352 * 4;
    int*   row_fill= (int*)ws;                          ws += 100352 * 4;
    int*   cnt_i   = (int*)ws;                          ws += 100352 * 4;
    int*   partial = (int*)ws;                          ws += 512 * 4;
    int*   gstart  = (int*)ws;                          ws += 516 * 4;
    unsigned short* W1t = (unsigned short*)ws;          ws += (size_t)128 * IND * 2;
    unsigned short* W2t = (unsigned short*)ws;          ws += (size_t)128 * HD * 2;
    int*   csr_src = (int*)ws;                          ws += (size_t)NE * 4;
    float* csr_nrm = (float*)ws;                        ws += (size_t)NE * 4;

    const int nblk = (NN + 255) / 256;           // 391
    const int eblk = (NE + 255) / 256;           // 6250
    const int mblk = (NN + 127) / 128;           // 782
    const int wblk = (NN * 32 + 255) / 256;      // 12500

    // CSR build + normalization + graph boundaries + weight prep
    k_zero <<<nblk, 256, 0, stream>>>(cnt_i);
    k_cnt  <<<eblk, 256, 0, stream>>>(ei, cnt_i);
    k_scan1<<<nblk, 256, 0, stream>>>(cnt_i, row_ptr, partial);
    k_scan2<<<1, 512, 0, stream>>>(partial, nblk);
    k_scan3<<<nblk, 256, 0, stream>>>(row_ptr, row_fill, cnt_i, partial, dinv);
    k_fill <<<eblk, 256, 0, stream>>>(ei, dinv, row_fill, csr_src, csr_nrm);
    k_gbound<<<nblk, 256, 0, stream>>>(batch, gstart);
    k_wprep<<<(128 * (IND + HD)) / 256, 256, 0, stream>>>(W1, W2, W1t, W2t);

    // layer 1: h1 = x@W1 -> bufA (bf16) ; gather (self-loop init) -> bufB (fp32)
    k_gemm_mfma<IND, false><<<mblk, 256, 0, stream>>>(x, W1t, nullptr, bufA, NN);
    k_gather<<<wblk, 256, 0, stream>>>(row_ptr, csr_src, csr_nrm, dinv, bufA, bufB);

    // layer 2: A = relu(bufB + b1) on load ; h2 -> bufA (bf16) ; gather -> bufB
    k_gemm_mfma<HD, true><<<mblk, 256, 0, stream>>>(bufB, W2t, b1, bufA, NN);
    k_gather<<<wblk, 256, 0, stream>>>(row_ptr, csr_src, csr_nrm, dinv, bufA, bufB);

    // fused pool + head
    k_pool2<<<NG, 128, 0, stream>>>(bufB, b2, gstart, fcw, fcb, out);
}

// Round 6
// 404.987 us; speedup vs baseline: 14.6695x; 1.0250x over previous
//
#include <hip/hip_runtime.h>
#include <hip/hip_bf16.h>

// Problem constants
constexpr int NN = 100000;       // nodes
constexpr int NE = 1600000;      // edges
constexpr int NG = 512;          // graphs
constexpr int IND = 384;         // in dim
constexpr int HD  = 128;         // hidden dim

typedef short bf16x8 __attribute__((ext_vector_type(8)));
typedef float f32x4  __attribute__((ext_vector_type(4)));

__device__ __forceinline__ unsigned short f2bf(float x) {
    unsigned int u = __builtin_bit_cast(unsigned int, x);
    u = (u + 0x7FFFu + ((u >> 16) & 1u)) >> 16;   // RNE
    return (unsigned short)u;
}
__device__ __forceinline__ float bf2f(unsigned short v) {
    return __builtin_bit_cast(float, (unsigned int)v << 16);
}

// ---------------------------------------------------------------------------
// zero: cnt_i = 0
__global__ __launch_bounds__(256) void k_zero(int* __restrict__ cnt_i) {
    int i = blockIdx.x * 256 + threadIdx.x;
    if (i < NN) cnt_i[i] = 0;
}

// int histogram over dst
__global__ __launch_bounds__(256) void k_cnt(const int* __restrict__ ei,
                                             int* __restrict__ cnt_i) {
    int e = blockIdx.x * 256 + threadIdx.x;
    if (e < NE) atomicAdd(&cnt_i[ei[NE + e]], 1);
}

// block-level exclusive scan of cnt_i -> row_ptr, block totals -> partial
__global__ __launch_bounds__(256) void k_scan1(const int* __restrict__ cnt_i,
                                               int* __restrict__ row_ptr,
                                               int* __restrict__ partial) {
    __shared__ int s[256];
    int t = threadIdx.x;
    int i = blockIdx.x * 256 + t;
    int v = (i < NN) ? cnt_i[i] : 0;
    s[t] = v;
    __syncthreads();
    for (int off = 1; off < 256; off <<= 1) {
        int x = (t >= off) ? s[t - off] : 0;
        __syncthreads();
        s[t] += x;
        __syncthreads();
    }
    if (i < NN) row_ptr[i] = s[t] - v;
    if (t == 255) partial[blockIdx.x] = s[255];
}

// exclusive scan of partial (nb <= 512), in place
__global__ __launch_bounds__(512) void k_scan2(int* __restrict__ partial, int nb) {
    __shared__ int s[512];
    int t = threadIdx.x;
    int v = (t < nb) ? partial[t] : 0;
    s[t] = v;
    __syncthreads();
    for (int off = 1; off < 512; off <<= 1) {
        int x = (t >= off) ? s[t - off] : 0;
        __syncthreads();
        s[t] += x;
        __syncthreads();
    }
    if (t < nb) partial[t] = s[t] - v;
}

// add block offsets; init fill cursors; dinv = rsqrt(deg_with_selfloop)
__global__ __launch_bounds__(256) void k_scan3(int* __restrict__ row_ptr,
                                               int* __restrict__ row_fill,
                                               const int* __restrict__ cnt_i,
                                               const int* __restrict__ partial,
                                               float* __restrict__ dinv) {
    int i = blockIdx.x * 256 + threadIdx.x;
    if (i < NN) {
        int r = row_ptr[i] + partial[blockIdx.x];
        row_ptr[i] = r;
        row_fill[i] = r;
        dinv[i] = rsqrtf((float)cnt_i[i] + 1.0f);
    }
    if (i == 0) row_ptr[NN] = NE;
}

// scatter edges into CSR slots (src only; norm folded into h pre/post scaling)
__global__ __launch_bounds__(256) void k_fill(const int* __restrict__ ei,
                                              int* __restrict__ row_fill,
                                              int* __restrict__ csr_src) {
    int e = blockIdx.x * 256 + threadIdx.x;
    if (e < NE) {
        int s = ei[e];
        int d = ei[NE + e];
        int pos = atomicAdd(&row_fill[d], 1);
        csr_src[pos] = s;
    }
}

// graph boundaries from sorted batch: gstart[g] = first node of graph g
__global__ __launch_bounds__(256) void k_gbound(const int* __restrict__ batch,
                                                int* __restrict__ gstart) {
    int i = blockIdx.x * 256 + threadIdx.x;
    if (i < NN) {
        int b = batch[i];
        int prev = (i == 0) ? -1 : batch[i - 1];
        for (int g = prev + 1; g <= b; ++g) gstart[g] = i;
        if (i == NN - 1)
            for (int g = b + 1; g <= NG; ++g) gstart[g] = NN;
    }
}

// weight prep: W1t[n][k] = bf16(W1[k][n]), W2t[n][k] = bf16(W2[k][n])
__global__ __launch_bounds__(256) void k_wprep(const float* __restrict__ W1,
                                               const float* __restrict__ W2,
                                               unsigned short* __restrict__ W1t,
                                               unsigned short* __restrict__ W2t) {
    int id = blockIdx.x * 256 + threadIdx.x;
    if (id < 128 * IND) {
        int n = id / IND, k = id - n * IND;
        W1t[id] = f2bf(W1[(size_t)k * HD + n]);
    } else {
        int id2 = id - 128 * IND;
        int n = id2 >> 7, k = id2 & 127;
        W2t[id2] = f2bf(W2[(size_t)k * HD + n]);
    }
}

// ---------------------------------------------------------------------------
// MFMA bf16 GEMM: Cout[M x 128](bf16) = dinv[row] * (A[M x K](fp32->bf16) @ Wt^T)
// (Wt is [128][K] bf16). If BR: A applies relu(a + bias) before conversion.
// 128x128 tile, BK=64, 4 waves each owning a 64x64 quadrant (4x4 16x16 frags).
// Output rows are pre-scaled by dinv (hs = dinv*h) for norm-free gathering.
template <int K, bool BR>
__global__ __launch_bounds__(256) void k_gemm_mfma(const float* __restrict__ A,
                                                   const unsigned short* __restrict__ Wt,
                                                   const float* __restrict__ bias,
                                                   const float* __restrict__ dinv,
                                                   unsigned short* __restrict__ Cout,
                                                   int M) {
    __shared__ unsigned short As[128][72];   // rows padded: stride 144B
    __shared__ unsigned short Bs[128][72];   // Bs[n][k]
    const int tid  = threadIdx.x;
    const int lane = tid & 63;
    const int wid  = tid >> 6;
    const int wm   = (wid & 1) * 64;
    const int wn   = (wid >> 1) * 64;
    const int m0   = blockIdx.x * 128;

    f32x4 acc[4][4];
#pragma unroll
    for (int i = 0; i < 4; ++i)
#pragma unroll
        for (int j = 0; j < 4; ++j) acc[i][j] = f32x4{0.f, 0.f, 0.f, 0.f};

    const int cg = tid & 15;      // A col group (4 fp32)
    const int rb = tid >> 4;      // A row base 0..15
    const int wrow = tid >> 1;    // Wt row 0..127
    const int wh   = tid & 1;     // Wt 32-col half

    for (int k0 = 0; k0 < K; k0 += 64) {
        // stage A tile (128 x 64 fp32 -> bf16)
#pragma unroll
        for (int p = 0; p < 8; ++p) {
            int r = rb + p * 16;
            int gr = m0 + r; if (gr > M - 1) gr = M - 1;
            float4 a = *(const float4*)(A + (size_t)gr * K + k0 + cg * 4);
            if (BR) {
                float4 bv = *(const float4*)(bias + k0 + cg * 4);
                a.x = fmaxf(a.x + bv.x, 0.0f);
                a.y = fmaxf(a.y + bv.y, 0.0f);
                a.z = fmaxf(a.z + bv.z, 0.0f);
                a.w = fmaxf(a.w + bv.w, 0.0f);
            }
            uint2 pk;
            pk.x = (unsigned)f2bf(a.x) | ((unsigned)f2bf(a.y) << 16);
            pk.y = (unsigned)f2bf(a.z) | ((unsigned)f2bf(a.w) << 16);
            *(uint2*)&As[r][cg * 4] = pk;
        }
        // stage Wt tile (128 rows x 64 bf16)
        {
            const uint4* src = (const uint4*)(Wt + (size_t)wrow * K + k0 + wh * 32);
#pragma unroll
            for (int q = 0; q < 4; ++q)
                *(uint4*)&Bs[wrow][wh * 32 + q * 8] = src[q];
        }
        __syncthreads();
#pragma unroll
        for (int ks = 0; ks < 2; ++ks) {
            bf16x8 af[4], bfr[4];
#pragma unroll
            for (int i = 0; i < 4; ++i)
                af[i] = *(const bf16x8*)&As[wm + i * 16 + (lane & 15)][ks * 32 + (lane >> 4) * 8];
#pragma unroll
            for (int i = 0; i < 4; ++i)
                bfr[i] = *(const bf16x8*)&Bs[wn + i * 16 + (lane & 15)][ks * 32 + (lane >> 4) * 8];
#pragma unroll
            for (int mi = 0; mi < 4; ++mi)
#pragma unroll
                for (int ni = 0; ni < 4; ++ni)
                    acc[mi][ni] = __builtin_amdgcn_mfma_f32_16x16x32_bf16(
                        af[mi], bfr[ni], acc[mi][ni], 0, 0, 0);
        }
        __syncthreads();
    }

    // epilogue: C/D frag layout col=lane&15, row=(lane>>4)*4+reg; emit bf16(dinv*acc)
#pragma unroll
    for (int mi = 0; mi < 4; ++mi) {
#pragma unroll
        for (int j = 0; j < 4; ++j) {
            int gr = m0 + wm + mi * 16 + (lane >> 4) * 4 + j;
            if (gr < M) {
                float dv = dinv[gr];
#pragma unroll
                for (int ni = 0; ni < 4; ++ni) {
                    int gc = wn + ni * 16 + (lane & 15);
                    Cout[(size_t)gr * HD + gc] = f2bf(acc[mi][ni][j] * dv);
                }
            }
        }
    }
}

// ---------------------------------------------------------------------------
// gather: out[n] = dinv[n] * (hs[n] + sum_{e in CSR row n} hs[src[e]])
// hs is bf16 [NN][128] pre-scaled by dinv; 32 lanes/node, 4 ch (8B) per lane.
// fp32 accumulate. BF16OUT selects output type (fp32 for GEMM2 input,
// bf16 for pool input). No atomics, out write-only.
template <bool BF16OUT>
__global__ __launch_bounds__(256) void k_gather(const int* __restrict__ row_ptr,
                                                const int* __restrict__ csr_src,
                                                const float* __restrict__ dinv,
                                                const unsigned short* __restrict__ hs,
                                                float* __restrict__ outf,
                                                unsigned short* __restrict__ outh) {
    int gid = blockIdx.x * 256 + threadIdx.x;
    int node = gid >> 5;
    int l = threadIdx.x & 31;
    if (node >= NN) return;
    int start = row_ptr[node];
    int end   = row_ptr[node + 1];
    uint2 hp = *(const uint2*)(hs + (size_t)node * HD + l * 4);
    float4 acc;
    acc.x = __builtin_bit_cast(float, hp.x << 16);
    acc.y = __builtin_bit_cast(float, hp.x & 0xffff0000u);
    acc.z = __builtin_bit_cast(float, hp.y << 16);
    acc.w = __builtin_bit_cast(float, hp.y & 0xffff0000u);
    for (int eb = start; eb < end; eb += 32) {
        int idx = eb + l;
        int src = 0;
        if (idx < end) src = csr_src[idx];
        int n = min(32, end - eb);
#pragma unroll 4
        for (int j = 0; j < n; ++j) {
            int s = __shfl(src, j, 32);
            uint2 pk = *(const uint2*)(hs + (size_t)s * HD + l * 4);
            acc.x += __builtin_bit_cast(float, pk.x << 16);
            acc.y += __builtin_bit_cast(float, pk.x & 0xffff0000u);
            acc.z += __builtin_bit_cast(float, pk.y << 16);
            acc.w += __builtin_bit_cast(float, pk.y & 0xffff0000u);
        }
    }
    float dv = dinv[node];
    acc.x *= dv; acc.y *= dv; acc.z *= dv; acc.w *= dv;
    if (BF16OUT) {
        uint2 pk;
        pk.x = (unsigned)f2bf(acc.x) | ((unsigned)f2bf(acc.y) << 16);
        pk.y = (unsigned)f2bf(acc.z) | ((unsigned)f2bf(acc.w) << 16);
        *(uint2*)(outh + (size_t)node * HD + l * 4) = pk;
    } else {
        *(float4*)(outf + (size_t)node * HD + l * 4) = acc;
    }
}

// ---------------------------------------------------------------------------
// pool + head fused: one block per graph (sorted batch -> contiguous ranges).
// acc2 is bf16. 512 threads: 4 row-parities x 128 channels.
__global__ __launch_bounds__(512) void k_pool2(const unsigned short* __restrict__ acc2,
                                               const float* __restrict__ b2,
                                               const int* __restrict__ gstart,
                                               const float* __restrict__ fcw,
                                               const float* __restrict__ fcb,
                                               float* __restrict__ out) {
    int g = blockIdx.x;
    int tid = threadIdx.x;
    int c = tid & 127;              // channel
    int par = tid >> 7;             // row parity 0..3
    int s = gstart[g];
    int e = gstart[g + 1];
    float bias = b2[c];
    float sum = 0.0f;
    for (int i = s + par; i < e; i += 4)
        sum += fmaxf(bf2f(acc2[(size_t)i * HD + c]) + bias, 0.0f);

    __shared__ float ps[4][128];
    ps[par][c] = sum;
    __syncthreads();

    float a0 = 0.0f, a1 = 0.0f;
    if (tid < 128) {
        float p = (ps[0][c] + ps[1][c] + ps[2][c] + ps[3][c]) /
                  fmaxf((float)(e - s), 1.0f);
        a0 = p * fcw[c * 2 + 0];
        a1 = p * fcw[c * 2 + 1];
    }
#pragma unroll
    for (int off = 32; off; off >>= 1) {
        a0 += __shfl_down(a0, off, 64);
        a1 += __shfl_down(a1, off, 64);
    }
    __shared__ float r0[8], r1[8];
    if ((tid & 63) == 0) { r0[tid >> 6] = a0; r1[tid >> 6] = a1; }
    __syncthreads();
    if (tid == 0) {
        float l0 = r0[0] + r0[1] + fcb[0];
        float l1 = r1[0] + r1[1] + fcb[1];
        float m = fmaxf(l0, l1);
        float lse = m + logf(__expf(l0 - m) + __expf(l1 - m));
        out[g * 2 + 0] = l0 - lse;
        out[g * 2 + 1] = l1 - lse;
    }
}

// ---------------------------------------------------------------------------
extern "C" void kernel_launch(void* const* d_in, const int* in_sizes, int n_in,
                              void* d_out, int out_size, void* d_ws, size_t ws_size,
                              hipStream_t stream) {
    const float* x    = (const float*)d_in[0];
    const int*   ei   = (const int*)d_in[1];   // [2][NE]
    const int*   batch= (const int*)d_in[2];   // [NN] (sorted)
    const float* W1   = (const float*)d_in[3];
    const float* b1   = (const float*)d_in[4];
    const float* W2   = (const float*)d_in[5];
    const float* b2   = (const float*)d_in[6];
    const float* fcw  = (const float*)d_in[7];
    const float* fcb  = (const float*)d_in[8];
    float* out = (float*)d_out;

    // workspace layout
    char* ws = (char*)d_ws;
    float* dinv    = (float*)ws;                        ws += 100352 * 4;
    unsigned short* bufA = (unsigned short*)ws;         ws += (size_t)NN * HD * 2;  // bf16 hs
    float* bufB    = (float*)ws;                        ws += (size_t)NN * HD * 4;  // fp32 agg1
    unsigned short* bufC = (unsigned short*)ws;         ws += (size_t)NN * HD * 2;  // bf16 agg2
    int*   row_ptr = (int*)ws;                          ws += 100352 * 4;
    int*   row_fill= (int*)ws;                          ws += 100352 * 4;
    int*   cnt_i   = (int*)ws;                          ws += 100352 * 4;
    int*   partial = (int*)ws;                          ws += 512 * 4;
    int*   gstart  = (int*)ws;                          ws += 516 * 4;
    unsigned short* W1t = (unsigned short*)ws;          ws += (size_t)128 * IND * 2;
    unsigned short* W2t = (unsigned short*)ws;          ws += (size_t)128 * HD * 2;
    int*   csr_src = (int*)ws;                          ws += (size_t)NE * 4;

    const int nblk = (NN + 255) / 256;           // 391
    const int eblk = (NE + 255) / 256;           // 6250
    const int mblk = (NN + 127) / 128;           // 782
    const int wblk = (NN * 32 + 255) / 256;      // 12500

    // CSR build + normalization + graph boundaries + weight prep
    k_zero <<<nblk, 256, 0, stream>>>(cnt_i);
    k_cnt  <<<eblk, 256, 0, stream>>>(ei, cnt_i);
    k_scan1<<<nblk, 256, 0, stream>>>(cnt_i, row_ptr, partial);
    k_scan2<<<1, 512, 0, stream>>>(partial, nblk);
    k_scan3<<<nblk, 256, 0, stream>>>(row_ptr, row_fill, cnt_i, partial, dinv);
    k_fill <<<eblk, 256, 0, stream>>>(ei, row_fill, csr_src);
    k_gbound<<<nblk, 256, 0, stream>>>(batch, gstart);
    k_wprep<<<(128 * (IND + HD)) / 256, 256, 0, stream>>>(W1, W2, W1t, W2t);

    // layer 1: hs1 = dinv*(x@W1) -> bufA (bf16) ; gather -> bufB (fp32)
    k_gemm_mfma<IND, false><<<mblk, 256, 0, stream>>>(x, W1t, nullptr, dinv, bufA, NN);
    k_gather<false><<<wblk, 256, 0, stream>>>(row_ptr, csr_src, dinv, bufA, bufB, nullptr);

    // layer 2: A = relu(bufB + b1) ; hs2 = dinv*(A@W2) -> bufA ; gather -> bufC (bf16)
    k_gemm_mfma<HD, true><<<mblk, 256, 0, stream>>>(bufB, W2t, b1, dinv, bufA, NN);
    k_gather<true><<<wblk, 256, 0, stream>>>(row_ptr, csr_src, dinv, bufA, nullptr, bufC);

    // fused pool + head
    k_pool2<<<NG, 512, 0, stream>>>(bufC, b2, gstart, fcw, fcb, out);
}

// Round 7
// 385.510 us; speedup vs baseline: 15.4106x; 1.0505x over previous
//
#include <hip/hip_runtime.h>
#include <hip/hip_bf16.h>

// Problem constants
constexpr int NN = 100000;       // nodes
constexpr int NE = 1600000;      // edges
constexpr int NG = 512;          // graphs
constexpr int IND = 384;         // in dim
constexpr int HD  = 128;         // hidden dim

// XCD-range filtering for scatter kernels
constexpr int NRANGE = 8;                 // MI355X XCD count
constexpr int RSPAN  = NN / NRANGE;       // 12500 nodes per range
constexpr int CHUNKS = 250;               // edge chunks
constexpr int CHUNK_E = NE / CHUNKS;      // 6400 edges per chunk

typedef short bf16x8 __attribute__((ext_vector_type(8)));
typedef float f32x4  __attribute__((ext_vector_type(4)));

__device__ __forceinline__ unsigned short f2bf(float x) {
    unsigned int u = __builtin_bit_cast(unsigned int, x);
    u = (u + 0x7FFFu + ((u >> 16) & 1u)) >> 16;   // RNE
    return (unsigned short)u;
}
__device__ __forceinline__ float bf2f(unsigned short v) {
    return __builtin_bit_cast(float, (unsigned int)v << 16);
}

// ---------------------------------------------------------------------------
// zero: cnt_i = 0
__global__ __launch_bounds__(256) void k_zero(int* __restrict__ cnt_i) {
    int i = blockIdx.x * 256 + threadIdx.x;
    if (i < NN) cnt_i[i] = 0;
}

// XCD-filtered int histogram over dst: block handles (range, chunk) pair;
// only edges with dst in range are counted -> atomics stay in one XCD's L2.
__global__ __launch_bounds__(256) void k_cnt(const int* __restrict__ ei,
                                             int* __restrict__ cnt_i) {
    int r = blockIdx.x & (NRANGE - 1);
    int c = blockIdx.x >> 3;
    int lo = r * RSPAN, hi = lo + RSPAN;
    int e0 = c * CHUNK_E;
    int e1 = min(e0 + CHUNK_E, NE);
    for (int e = e0 + threadIdx.x; e < e1; e += 256) {
        int d = ei[NE + e];
        if (d >= lo && d < hi) atomicAdd(&cnt_i[d], 1);
    }
}

// block-level exclusive scan of cnt_i -> row_ptr, block totals -> partial
__global__ __launch_bounds__(256) void k_scan1(const int* __restrict__ cnt_i,
                                               int* __restrict__ row_ptr,
                                               int* __restrict__ partial) {
    __shared__ int s[256];
    int t = threadIdx.x;
    int i = blockIdx.x * 256 + t;
    int v = (i < NN) ? cnt_i[i] : 0;
    s[t] = v;
    __syncthreads();
    for (int off = 1; off < 256; off <<= 1) {
        int x = (t >= off) ? s[t - off] : 0;
        __syncthreads();
        s[t] += x;
        __syncthreads();
    }
    if (i < NN) row_ptr[i] = s[t] - v;
    if (t == 255) partial[blockIdx.x] = s[255];
}

// exclusive scan of partial (nb <= 512), in place
__global__ __launch_bounds__(512) void k_scan2(int* __restrict__ partial, int nb) {
    __shared__ int s[512];
    int t = threadIdx.x;
    int v = (t < nb) ? partial[t] : 0;
    s[t] = v;
    __syncthreads();
    for (int off = 1; off < 512; off <<= 1) {
        int x = (t >= off) ? s[t - off] : 0;
        __syncthreads();
        s[t] += x;
        __syncthreads();
    }
    if (t < nb) partial[t] = s[t] - v;
}

// add block offsets; init fill cursors; dinv = rsqrt(deg_with_selfloop)
__global__ __launch_bounds__(256) void k_scan3(int* __restrict__ row_ptr,
                                               int* __restrict__ row_fill,
                                               const int* __restrict__ cnt_i,
                                               const int* __restrict__ partial,
                                               float* __restrict__ dinv) {
    int i = blockIdx.x * 256 + threadIdx.x;
    if (i < NN) {
        int r = row_ptr[i] + partial[blockIdx.x];
        row_ptr[i] = r;
        row_fill[i] = r;
        dinv[i] = rsqrtf((float)cnt_i[i] + 1.0f);
    }
    if (i == 0) row_ptr[NN] = NE;
}

// XCD-filtered CSR fill: block handles (range, chunk); only edges with dst in
// range are written. Cursor atomics + csr_src lines stay in one XCD's L2, so
// each 64B line accumulates ~16 writes before one writeback.
__global__ __launch_bounds__(256) void k_fill(const int* __restrict__ ei,
                                              int* __restrict__ row_fill,
                                              int* __restrict__ csr_src) {
    int r = blockIdx.x & (NRANGE - 1);
    int c = blockIdx.x >> 3;
    int lo = r * RSPAN, hi = lo + RSPAN;
    int e0 = c * CHUNK_E;
    int e1 = min(e0 + CHUNK_E, NE);
    for (int e = e0 + threadIdx.x; e < e1; e += 256) {
        int d = ei[NE + e];
        if (d >= lo && d < hi) {
            int s = ei[e];
            int pos = atomicAdd(&row_fill[d], 1);
            csr_src[pos] = s;
        }
    }
}

// graph boundaries from sorted batch: gstart[g] = first node of graph g
__global__ __launch_bounds__(256) void k_gbound(const int* __restrict__ batch,
                                                int* __restrict__ gstart) {
    int i = blockIdx.x * 256 + threadIdx.x;
    if (i < NN) {
        int b = batch[i];
        int prev = (i == 0) ? -1 : batch[i - 1];
        for (int g = prev + 1; g <= b; ++g) gstart[g] = i;
        if (i == NN - 1)
            for (int g = b + 1; g <= NG; ++g) gstart[g] = NN;
    }
}

// weight prep: W1t[n][k] = bf16(W1[k][n]), W2t[n][k] = bf16(W2[k][n])
__global__ __launch_bounds__(256) void k_wprep(const float* __restrict__ W1,
                                               const float* __restrict__ W2,
                                               unsigned short* __restrict__ W1t,
                                               unsigned short* __restrict__ W2t) {
    int id = blockIdx.x * 256 + threadIdx.x;
    if (id < 128 * IND) {
        int n = id / IND, k = id - n * IND;
        W1t[id] = f2bf(W1[(size_t)k * HD + n]);
    } else {
        int id2 = id - 128 * IND;
        int n = id2 >> 7, k = id2 & 127;
        W2t[id2] = f2bf(W2[(size_t)k * HD + n]);
    }
}

// ---------------------------------------------------------------------------
// MFMA bf16 GEMM: Cout[M x 128](bf16) = dinv[row] * (A[M x K](fp32->bf16) @ Wt^T)
// (Wt is [128][K] bf16). If BR: A applies relu(a + bias) before conversion.
// 128x128 tile, BK=64, 4 waves each owning a 64x64 quadrant (4x4 16x16 frags).
template <int K, bool BR>
__global__ __launch_bounds__(256) void k_gemm_mfma(const float* __restrict__ A,
                                                   const unsigned short* __restrict__ Wt,
                                                   const float* __restrict__ bias,
                                                   const float* __restrict__ dinv,
                                                   unsigned short* __restrict__ Cout,
                                                   int M) {
    __shared__ unsigned short As[128][72];   // rows padded: stride 144B
    __shared__ unsigned short Bs[128][72];   // Bs[n][k]
    const int tid  = threadIdx.x;
    const int lane = tid & 63;
    const int wid  = tid >> 6;
    const int wm   = (wid & 1) * 64;
    const int wn   = (wid >> 1) * 64;
    const int m0   = blockIdx.x * 128;

    f32x4 acc[4][4];
#pragma unroll
    for (int i = 0; i < 4; ++i)
#pragma unroll
        for (int j = 0; j < 4; ++j) acc[i][j] = f32x4{0.f, 0.f, 0.f, 0.f};

    const int cg = tid & 15;      // A col group (4 fp32)
    const int rb = tid >> 4;      // A row base 0..15
    const int wrow = tid >> 1;    // Wt row 0..127
    const int wh   = tid & 1;     // Wt 32-col half

    for (int k0 = 0; k0 < K; k0 += 64) {
        // stage A tile (128 x 64 fp32 -> bf16)
#pragma unroll
        for (int p = 0; p < 8; ++p) {
            int r = rb + p * 16;
            int gr = m0 + r; if (gr > M - 1) gr = M - 1;
            float4 a = *(const float4*)(A + (size_t)gr * K + k0 + cg * 4);
            if (BR) {
                float4 bv = *(const float4*)(bias + k0 + cg * 4);
                a.x = fmaxf(a.x + bv.x, 0.0f);
                a.y = fmaxf(a.y + bv.y, 0.0f);
                a.z = fmaxf(a.z + bv.z, 0.0f);
                a.w = fmaxf(a.w + bv.w, 0.0f);
            }
            uint2 pk;
            pk.x = (unsigned)f2bf(a.x) | ((unsigned)f2bf(a.y) << 16);
            pk.y = (unsigned)f2bf(a.z) | ((unsigned)f2bf(a.w) << 16);
            *(uint2*)&As[r][cg * 4] = pk;
        }
        // stage Wt tile (128 rows x 64 bf16)
        {
            const uint4* src = (const uint4*)(Wt + (size_t)wrow * K + k0 + wh * 32);
#pragma unroll
            for (int q = 0; q < 4; ++q)
                *(uint4*)&Bs[wrow][wh * 32 + q * 8] = src[q];
        }
        __syncthreads();
#pragma unroll
        for (int ks = 0; ks < 2; ++ks) {
            bf16x8 af[4], bfr[4];
#pragma unroll
            for (int i = 0; i < 4; ++i)
                af[i] = *(const bf16x8*)&As[wm + i * 16 + (lane & 15)][ks * 32 + (lane >> 4) * 8];
#pragma unroll
            for (int i = 0; i < 4; ++i)
                bfr[i] = *(const bf16x8*)&Bs[wn + i * 16 + (lane & 15)][ks * 32 + (lane >> 4) * 8];
#pragma unroll
            for (int mi = 0; mi < 4; ++mi)
#pragma unroll
                for (int ni = 0; ni < 4; ++ni)
                    acc[mi][ni] = __builtin_amdgcn_mfma_f32_16x16x32_bf16(
                        af[mi], bfr[ni], acc[mi][ni], 0, 0, 0);
        }
        __syncthreads();
    }

    // epilogue: C/D frag layout col=lane&15, row=(lane>>4)*4+reg; emit bf16(dinv*acc)
#pragma unroll
    for (int mi = 0; mi < 4; ++mi) {
#pragma unroll
        for (int j = 0; j < 4; ++j) {
            int gr = m0 + wm + mi * 16 + (lane >> 4) * 4 + j;
            if (gr < M) {
                float dv = dinv[gr];
#pragma unroll
                for (int ni = 0; ni < 4; ++ni) {
                    int gc = wn + ni * 16 + (lane & 15);
                    Cout[(size_t)gr * HD + gc] = f2bf(acc[mi][ni][j] * dv);
                }
            }
        }
    }
}

// ---------------------------------------------------------------------------
// gather: out[n] = dinv[n] * (hs[n] + sum_{e in CSR row n} hs[src[e]])
// hs is bf16 [NN][128] pre-scaled by dinv; 32 lanes/node, 4 ch (8B) per lane.
// fp32 accumulate. BF16OUT selects output type. No atomics, out write-only.
template <bool BF16OUT>
__global__ __launch_bounds__(256) void k_gather(const int* __restrict__ row_ptr,
                                                const int* __restrict__ csr_src,
                                                const float* __restrict__ dinv,
                                                const unsigned short* __restrict__ hs,
                                                float* __restrict__ outf,
                                                unsigned short* __restrict__ outh) {
    int gid = blockIdx.x * 256 + threadIdx.x;
    int node = gid >> 5;
    int l = threadIdx.x & 31;
    if (node >= NN) return;
    int start = row_ptr[node];
    int end   = row_ptr[node + 1];
    uint2 hp = *(const uint2*)(hs + (size_t)node * HD + l * 4);
    float4 acc;
    acc.x = __builtin_bit_cast(float, hp.x << 16);
    acc.y = __builtin_bit_cast(float, hp.x & 0xffff0000u);
    acc.z = __builtin_bit_cast(float, hp.y << 16);
    acc.w = __builtin_bit_cast(float, hp.y & 0xffff0000u);
    for (int eb = start; eb < end; eb += 32) {
        int idx = eb + l;
        int src = 0;
        if (idx < end) src = csr_src[idx];
        int n = min(32, end - eb);
#pragma unroll 4
        for (int j = 0; j < n; ++j) {
            int s = __shfl(src, j, 32);
            uint2 pk = *(const uint2*)(hs + (size_t)s * HD + l * 4);
            acc.x += __builtin_bit_cast(float, pk.x << 16);
            acc.y += __builtin_bit_cast(float, pk.x & 0xffff0000u);
            acc.z += __builtin_bit_cast(float, pk.y << 16);
            acc.w += __builtin_bit_cast(float, pk.y & 0xffff0000u);
        }
    }
    float dv = dinv[node];
    acc.x *= dv; acc.y *= dv; acc.z *= dv; acc.w *= dv;
    if (BF16OUT) {
        uint2 pk;
        pk.x = (unsigned)f2bf(acc.x) | ((unsigned)f2bf(acc.y) << 16);
        pk.y = (unsigned)f2bf(acc.z) | ((unsigned)f2bf(acc.w) << 16);
        *(uint2*)(outh + (size_t)node * HD + l * 4) = pk;
    } else {
        *(float4*)(outf + (size_t)node * HD + l * 4) = acc;
    }
}

// ---------------------------------------------------------------------------
// pool + head fused: one block per graph (sorted batch -> contiguous ranges).
// acc2 is bf16. 512 threads: 4 row-parities x 128 channels.
__global__ __launch_bounds__(512) void k_pool2(const unsigned short* __restrict__ acc2,
                                               const float* __restrict__ b2,
                                               const int* __restrict__ gstart,
                                               const float* __restrict__ fcw,
                                               const float* __restrict__ fcb,
                                               float* __restrict__ out) {
    int g = blockIdx.x;
    int tid = threadIdx.x;
    int c = tid & 127;              // channel
    int par = tid >> 7;             // row parity 0..3
    int s = gstart[g];
    int e = gstart[g + 1];
    float bias = b2[c];
    float sum = 0.0f;
    for (int i = s + par; i < e; i += 4)
        sum += fmaxf(bf2f(acc2[(size_t)i * HD + c]) + bias, 0.0f);

    __shared__ float ps[4][128];
    ps[par][c] = sum;
    __syncthreads();

    float a0 = 0.0f, a1 = 0.0f;
    if (tid < 128) {
        float p = (ps[0][c] + ps[1][c] + ps[2][c] + ps[3][c]) /
                  fmaxf((float)(e - s), 1.0f);
        a0 = p * fcw[c * 2 + 0];
        a1 = p * fcw[c * 2 + 1];
    }
#pragma unroll
    for (int off = 32; off; off >>= 1) {
        a0 += __shfl_down(a0, off, 64);
        a1 += __shfl_down(a1, off, 64);
    }
    __shared__ float r0[8], r1[8];
    if ((tid & 63) == 0) { r0[tid >> 6] = a0; r1[tid >> 6] = a1; }
    __syncthreads();
    if (tid == 0) {
        float l0 = r0[0] + r0[1] + fcb[0];
        float l1 = r1[0] + r1[1] + fcb[1];
        float m = fmaxf(l0, l1);
        float lse = m + logf(__expf(l0 - m) + __expf(l1 - m));
        out[g * 2 + 0] = l0 - lse;
        out[g * 2 + 1] = l1 - lse;
    }
}

// ---------------------------------------------------------------------------
extern "C" void kernel_launch(void* const* d_in, const int* in_sizes, int n_in,
                              void* d_out, int out_size, void* d_ws, size_t ws_size,
                              hipStream_t stream) {
    const float* x    = (const float*)d_in[0];
    const int*   ei   = (const int*)d_in[1];   // [2][NE]
    const int*   batch= (const int*)d_in[2];   // [NN] (sorted)
    const float* W1   = (const float*)d_in[3];
    const float* b1   = (const float*)d_in[4];
    const float* W2   = (const float*)d_in[5];
    const float* b2   = (const float*)d_in[6];
    const float* fcw  = (const float*)d_in[7];
    const float* fcb  = (const float*)d_in[8];
    float* out = (float*)d_out;

    // workspace layout
    char* ws = (char*)d_ws;
    float* dinv    = (float*)ws;                        ws += 100352 * 4;
    unsigned short* bufA = (unsigned short*)ws;         ws += (size_t)NN * HD * 2;  // bf16 hs
    float* bufB    = (float*)ws;                        ws += (size_t)NN * HD * 4;  // fp32 agg1
    unsigned short* bufC = (unsigned short*)ws;         ws += (size_t)NN * HD * 2;  // bf16 agg2
    int*   row_ptr = (int*)ws;                          ws += 100352 * 4;
    int*   row_fill= (int*)ws;                          ws += 100352 * 4;
    int*   cnt_i   = (int*)ws;                          ws += 100352 * 4;
    int*   partial = (int*)ws;                          ws += 512 * 4;
    int*   gstart  = (int*)ws;                          ws += 516 * 4;
    unsigned short* W1t = (unsigned short*)ws;          ws += (size_t)128 * IND * 2;
    unsigned short* W2t = (unsigned short*)ws;          ws += (size_t)128 * HD * 2;
    int*   csr_src = (int*)ws;                          ws += (size_t)NE * 4;

    const int nblk = (NN + 255) / 256;           // 391
    const int fblk = NRANGE * CHUNKS;            // 2000 (range x chunk)
    const int mblk = (NN + 127) / 128;           // 782
    const int wblk = (NN * 32 + 255) / 256;      // 12500

    // CSR build + normalization + graph boundaries + weight prep
    k_zero <<<nblk, 256, 0, stream>>>(cnt_i);
    k_cnt  <<<fblk, 256, 0, stream>>>(ei, cnt_i);
    k_scan1<<<nblk, 256, 0, stream>>>(cnt_i, row_ptr, partial);
    k_scan2<<<1, 512, 0, stream>>>(partial, nblk);
    k_scan3<<<nblk, 256, 0, stream>>>(row_ptr, row_fill, cnt_i, partial, dinv);
    k_fill <<<fblk, 256, 0, stream>>>(ei, row_fill, csr_src);
    k_gbound<<<nblk, 256, 0, stream>>>(batch, gstart);
    k_wprep<<<(128 * (IND + HD)) / 256, 256, 0, stream>>>(W1, W2, W1t, W2t);

    // layer 1: hs1 = dinv*(x@W1) -> bufA (bf16) ; gather -> bufB (fp32)
    k_gemm_mfma<IND, false><<<mblk, 256, 0, stream>>>(x, W1t, nullptr, dinv, bufA, NN);
    k_gather<false><<<wblk, 256, 0, stream>>>(row_ptr, csr_src, dinv, bufA, bufB, nullptr);

    // layer 2: A = relu(bufB + b1) ; hs2 = dinv*(A@W2) -> bufA ; gather -> bufC (bf16)
    k_gemm_mfma<HD, true><<<mblk, 256, 0, stream>>>(bufB, W2t, b1, dinv, bufA, NN);
    k_gather<true><<<wblk, 256, 0, stream>>>(row_ptr, csr_src, dinv, bufA, nullptr, bufC);

    // fused pool + head
    k_pool2<<<NG, 512, 0, stream>>>(bufC, b2, gstart, fcw, fcb, out);
}

// Round 8
// 344.543 us; speedup vs baseline: 17.2430x; 1.1189x over previous
//
#include <hip/hip_runtime.h>
#include <hip/hip_bf16.h>

// Problem constants
constexpr int NN = 100000;       // nodes
constexpr int NE = 1600000;      // edges
constexpr int NG = 512;          // graphs
constexpr int IND = 384;         // in dim
constexpr int HD  = 128;         // hidden dim

// CSR bucket-sort geometry
constexpr int NR      = 64;              // node ranges
constexpr int RSPAN2  = 1563;            // nodes per range (64*1563 >= NN)
constexpr int CHUNKS2 = 800;             // edge chunks
constexpr int CHUNK2_E = NE / CHUNKS2;   // 2000 edges per chunk

typedef short bf16x8 __attribute__((ext_vector_type(8)));
typedef float f32x4  __attribute__((ext_vector_type(4)));
typedef unsigned short ushort8 __attribute__((ext_vector_type(8)));

__device__ __forceinline__ unsigned short f2bf(float x) {
    unsigned int u = __builtin_bit_cast(unsigned int, x);
    u = (u + 0x7FFFu + ((u >> 16) & 1u)) >> 16;   // RNE
    return (unsigned short)u;
}
__device__ __forceinline__ float bf2f(unsigned short v) {
    return __builtin_bit_cast(float, (unsigned int)v << 16);
}

// ---------------------------------------------------------------------------
// GEMM body (device): Cout[M x 128](bf16) = [dinv[row] *] (A(fp32->bf16) @ Wt^T)
// Wt is [128][K] bf16. If BR: A applies relu(a + bias) before conversion.
// 128x128 tile, BK=64, 4 waves each owning a 64x64 quadrant (4x4 16x16 frags).
template <int K, bool BR, bool SC>
__device__ __forceinline__ void gemm_body(int bid,
                                          const float* __restrict__ A,
                                          const unsigned short* __restrict__ Wt,
                                          const float* __restrict__ bias,
                                          const float* __restrict__ dinv,
                                          unsigned short* __restrict__ Cout,
                                          int M,
                                          unsigned short (*As)[72],
                                          unsigned short (*Bs)[72]) {
    const int tid  = threadIdx.x;
    const int lane = tid & 63;
    const int wid  = tid >> 6;
    const int wm   = (wid & 1) * 64;
    const int wn   = (wid >> 1) * 64;
    const int m0   = bid * 128;

    f32x4 acc[4][4];
#pragma unroll
    for (int i = 0; i < 4; ++i)
#pragma unroll
        for (int j = 0; j < 4; ++j) acc[i][j] = f32x4{0.f, 0.f, 0.f, 0.f};

    const int cg = tid & 15;      // A col group (4 fp32)
    const int rb = tid >> 4;      // A row base 0..15
    const int wrow = tid >> 1;    // Wt row 0..127
    const int wh   = tid & 1;     // Wt 32-col half

    for (int k0 = 0; k0 < K; k0 += 64) {
        // stage A tile (128 x 64 fp32 -> bf16)
#pragma unroll
        for (int p = 0; p < 8; ++p) {
            int r = rb + p * 16;
            int gr = m0 + r; if (gr > M - 1) gr = M - 1;
            float4 a = *(const float4*)(A + (size_t)gr * K + k0 + cg * 4);
            if (BR) {
                float4 bv = *(const float4*)(bias + k0 + cg * 4);
                a.x = fmaxf(a.x + bv.x, 0.0f);
                a.y = fmaxf(a.y + bv.y, 0.0f);
                a.z = fmaxf(a.z + bv.z, 0.0f);
                a.w = fmaxf(a.w + bv.w, 0.0f);
            }
            uint2 pk;
            pk.x = (unsigned)f2bf(a.x) | ((unsigned)f2bf(a.y) << 16);
            pk.y = (unsigned)f2bf(a.z) | ((unsigned)f2bf(a.w) << 16);
            *(uint2*)&As[r][cg * 4] = pk;
        }
        // stage Wt tile (128 rows x 64 bf16)
        {
            const uint4* src = (const uint4*)(Wt + (size_t)wrow * K + k0 + wh * 32);
#pragma unroll
            for (int q = 0; q < 4; ++q)
                *(uint4*)&Bs[wrow][wh * 32 + q * 8] = src[q];
        }
        __syncthreads();
#pragma unroll
        for (int ks = 0; ks < 2; ++ks) {
            bf16x8 af[4], bfr[4];
#pragma unroll
            for (int i = 0; i < 4; ++i)
                af[i] = *(const bf16x8*)&As[wm + i * 16 + (lane & 15)][ks * 32 + (lane >> 4) * 8];
#pragma unroll
            for (int i = 0; i < 4; ++i)
                bfr[i] = *(const bf16x8*)&Bs[wn + i * 16 + (lane & 15)][ks * 32 + (lane >> 4) * 8];
#pragma unroll
            for (int mi = 0; mi < 4; ++mi)
#pragma unroll
                for (int ni = 0; ni < 4; ++ni)
                    acc[mi][ni] = __builtin_amdgcn_mfma_f32_16x16x32_bf16(
                        af[mi], bfr[ni], acc[mi][ni], 0, 0, 0);
        }
        __syncthreads();
    }

    // epilogue: C/D frag layout col=lane&15, row=(lane>>4)*4+reg
#pragma unroll
    for (int mi = 0; mi < 4; ++mi) {
#pragma unroll
        for (int j = 0; j < 4; ++j) {
            int gr = m0 + wm + mi * 16 + (lane >> 4) * 4 + j;
            if (gr < M) {
                float dv = SC ? dinv[gr] : 1.0f;
#pragma unroll
                for (int ni = 0; ni < 4; ++ni) {
                    int gc = wn + ni * 16 + (lane & 15);
                    Cout[(size_t)gr * HD + gc] = f2bf(acc[mi][ni][j] * dv);
                }
            }
        }
    }
}

template <int K, bool BR, bool SC>
__global__ __launch_bounds__(256) void k_gemm_mfma(const float* __restrict__ A,
                                                   const unsigned short* __restrict__ Wt,
                                                   const float* __restrict__ bias,
                                                   const float* __restrict__ dinv,
                                                   unsigned short* __restrict__ Cout,
                                                   int M) {
    __shared__ unsigned short As[128][72];
    __shared__ unsigned short Bs[128][72];
    gemm_body<K, BR, SC>(blockIdx.x, A, Wt, bias, dinv, Cout, M, As, Bs);
}

// ---------------------------------------------------------------------------
// P0 fused prologue: zero cnt_i | weight transpose+convert | graph boundaries
constexpr int P0_Z = (NN + 255) / 256;   // 391
constexpr int P0_W = 128 * (IND + HD) / 256; // 256
constexpr int P0_G = (NN + 255) / 256;   // 391
__global__ __launch_bounds__(256) void k_p0(int* __restrict__ cnt_i,
                                            const float* __restrict__ W1,
                                            const float* __restrict__ W2,
                                            unsigned short* __restrict__ W1t,
                                            unsigned short* __restrict__ W2t,
                                            const int* __restrict__ batch,
                                            int* __restrict__ gstart) {
    int bid = blockIdx.x;
    if (bid < P0_Z) {
        int i = bid * 256 + threadIdx.x;
        if (i < NN) cnt_i[i] = 0;
    } else if (bid < P0_Z + P0_W) {
        int id = (bid - P0_Z) * 256 + threadIdx.x;
        if (id < 128 * IND) {
            int n = id / IND, k = id - n * IND;
            W1t[id] = f2bf(W1[(size_t)k * HD + n]);
        } else {
            int id2 = id - 128 * IND;
            int n = id2 >> 7, k = id2 & 127;
            W2t[id2] = f2bf(W2[(size_t)k * HD + n]);
        }
    } else {
        int i = (bid - P0_Z - P0_W) * 256 + threadIdx.x;
        if (i < NN) {
            int b = batch[i];
            int prev = (i == 0) ? -1 : batch[i - 1];
            for (int g = prev + 1; g <= b; ++g) gstart[g] = i;
            if (i == NN - 1)
                for (int g = b + 1; g <= NG; ++g) gstart[g] = NN;
        }
    }
}

// ---------------------------------------------------------------------------
// P1 fused: GEMM1 (unscaled h1 -> bufA) | degree count | per-chunk range hist
constexpr int GB1 = (NN + 127) / 128;    // 782 GEMM blocks
constexpr int CB  = 391;                 // cnt blocks
__global__ __launch_bounds__(256) void k_p1(const float* __restrict__ x,
                                            const unsigned short* __restrict__ W1t,
                                            unsigned short* __restrict__ bufA,
                                            const int* __restrict__ ei,
                                            int* __restrict__ cnt_i,
                                            int* __restrict__ cnt2) {
    __shared__ unsigned short As[128][72];
    __shared__ unsigned short Bs[128][72];
    __shared__ int hist[NR];
    int bid = blockIdx.x;
    int t = threadIdx.x;
    if (bid < GB1) {
        gemm_body<IND, false, false>(bid, x, W1t, nullptr, nullptr, bufA, NN, As, Bs);
    } else if (bid < GB1 + CB) {
        for (int e = (bid - GB1) * 256 + t; e < NE; e += CB * 256)
            atomicAdd(&cnt_i[ei[NE + e]], 1);
    } else {
        int c = bid - GB1 - CB;
        if (t < NR) hist[t] = 0;
        __syncthreads();
        int e0 = c * CHUNK2_E;
        for (int k = t; k < CHUNK2_E; k += 256)
            atomicAdd(&hist[ei[NE + e0 + k] / RSPAN2], 1);
        __syncthreads();
        if (t < NR) cnt2[c * NR + t] = hist[t];
    }
}

// ---------------------------------------------------------------------------
// block-level exclusive scan of cnt_i -> row_ptr, block totals -> partial
__global__ __launch_bounds__(256) void k_scan1(const int* __restrict__ cnt_i,
                                               int* __restrict__ row_ptr,
                                               int* __restrict__ partial) {
    __shared__ int s[256];
    int t = threadIdx.x;
    int i = blockIdx.x * 256 + t;
    int v = (i < NN) ? cnt_i[i] : 0;
    s[t] = v;
    __syncthreads();
    for (int off = 1; off < 256; off <<= 1) {
        int x = (t >= off) ? s[t - off] : 0;
        __syncthreads();
        s[t] += x;
        __syncthreads();
    }
    if (i < NN) row_ptr[i] = s[t] - v;
    if (t == 255) partial[blockIdx.x] = s[255];
}

// exclusive scan of partial (nb <= 512), in place
__global__ __launch_bounds__(512) void k_scan2(int* __restrict__ partial, int nb) {
    __shared__ int s[512];
    int t = threadIdx.x;
    int v = (t < nb) ? partial[t] : 0;
    s[t] = v;
    __syncthreads();
    for (int off = 1; off < 512; off <<= 1) {
        int x = (t >= off) ? s[t - off] : 0;
        __syncthreads();
        s[t] += x;
        __syncthreads();
    }
    if (t < nb) partial[t] = s[t] - v;
}

// add block offsets; dinv = rsqrt(deg_with_selfloop); row_ptr[NN] = NE
__global__ __launch_bounds__(256) void k_scan3(int* __restrict__ row_ptr,
                                               const int* __restrict__ cnt_i,
                                               const int* __restrict__ partial,
                                               float* __restrict__ dinv) {
    int i = blockIdx.x * 256 + threadIdx.x;
    if (i < NN) {
        row_ptr[i] += partial[blockIdx.x];
        dinv[i] = rsqrtf((float)cnt_i[i] + 1.0f);
    }
    if (i == 0) row_ptr[NN] = NE;
}

// ---------------------------------------------------------------------------
// P2 fused: F2 (base2[chunk][r] = row_ptr[r*RSPAN2] + prefix of cnt2 over
// chunks) | scale bufA rows by dinv (hs1 = dinv * h1)
constexpr int P2_SC = 256;   // scale blocks
__global__ __launch_bounds__(1024) void k_p2(const int* __restrict__ cnt2,
                                             const int* __restrict__ row_ptr,
                                             int* __restrict__ base2,
                                             const float* __restrict__ dinv,
                                             unsigned short* __restrict__ bufA) {
    __shared__ int s[1024];
    int bid = blockIdx.x;
    int t = threadIdx.x;
    if (bid < NR) {
        int r = bid;
        int v = (t < CHUNKS2) ? cnt2[t * NR + r] : 0;
        s[t] = v;
        __syncthreads();
        for (int off = 1; off < 1024; off <<= 1) {
            int x = (t >= off) ? s[t - off] : 0;
            __syncthreads();
            s[t] += x;
            __syncthreads();
        }
        if (t < CHUNKS2) base2[t * NR + r] = row_ptr[r * RSPAN2] + s[t] - v;
    } else {
        constexpr int NVEC = NN * HD / 8;
        for (int idx = (bid - NR) * 1024 + t; idx < NVEC; idx += P2_SC * 1024) {
            ushort8 v = *(const ushort8*)(bufA + (size_t)idx * 8);
            float dv = dinv[idx >> 4];
#pragma unroll
            for (int j = 0; j < 8; ++j) v[j] = f2bf(bf2f(v[j]) * dv);
            *(ushort8*)(bufA + (size_t)idx * 8) = v;
        }
    }
}

// F3: bucket edges by range at deterministic per-chunk offsets (LDS cursors)
__global__ __launch_bounds__(256) void k_f3(const int* __restrict__ ei,
                                            const int* __restrict__ base2,
                                            int2* __restrict__ ebuf) {
    __shared__ int cur[NR];
    int c = blockIdx.x;
    int t = threadIdx.x;
    if (t < NR) cur[t] = base2[c * NR + t];
    __syncthreads();
    int e0 = c * CHUNK2_E;
    for (int k = t; k < CHUNK2_E; k += 256) {
        int e = e0 + k;
        int sv = ei[e];
        int d = ei[NE + e];
        int pos = atomicAdd(&cur[d / RSPAN2], 1);
        ebuf[pos] = make_int2(sv, d);
    }
}

// F4: one block per range; scatter bucketed edges into exact CSR slots via
// LDS per-node cursors (range's CSR span is L2-local, no global atomics)
__global__ __launch_bounds__(1024) void k_f4(const int* __restrict__ row_ptr,
                                             const int2* __restrict__ ebuf,
                                             int* __restrict__ csr_src) {
    __shared__ int cur[RSPAN2];
    int r = blockIdx.x;
    int lo = r * RSPAN2;
    int hi = min(lo + RSPAN2, NN);
    int t = threadIdx.x;
    for (int i = t; i < hi - lo; i += 1024) cur[i] = row_ptr[lo + i];
    __syncthreads();
    int es = row_ptr[lo];
    int ee = row_ptr[hi];
    for (int e = es + t; e < ee; e += 1024) {
        int2 ed = ebuf[e];
        int pos = atomicAdd(&cur[ed.y - lo], 1);
        csr_src[pos] = ed.x;
    }
}

// ---------------------------------------------------------------------------
// gather: out[n] = dinv[n] * (hs[n] + sum_{e in CSR row n} hs[src[e]])
// hs is bf16 [NN][128] pre-scaled by dinv; 32 lanes/node, 4 ch (8B) per lane.
template <bool BF16OUT>
__global__ __launch_bounds__(256) void k_gather(const int* __restrict__ row_ptr,
                                                const int* __restrict__ csr_src,
                                                const float* __restrict__ dinv,
                                                const unsigned short* __restrict__ hs,
                                                float* __restrict__ outf,
                                                unsigned short* __restrict__ outh) {
    int gid = blockIdx.x * 256 + threadIdx.x;
    int node = gid >> 5;
    int l = threadIdx.x & 31;
    if (node >= NN) return;
    int start = row_ptr[node];
    int end   = row_ptr[node + 1];
    uint2 hp = *(const uint2*)(hs + (size_t)node * HD + l * 4);
    float4 acc;
    acc.x = __builtin_bit_cast(float, hp.x << 16);
    acc.y = __builtin_bit_cast(float, hp.x & 0xffff0000u);
    acc.z = __builtin_bit_cast(float, hp.y << 16);
    acc.w = __builtin_bit_cast(float, hp.y & 0xffff0000u);
    for (int eb = start; eb < end; eb += 32) {
        int idx = eb + l;
        int src = 0;
        if (idx < end) src = csr_src[idx];
        int n = min(32, end - eb);
#pragma unroll 8
        for (int j = 0; j < n; ++j) {
            int s = __shfl(src, j, 32);
            uint2 pk = *(const uint2*)(hs + (size_t)s * HD + l * 4);
            acc.x += __builtin_bit_cast(float, pk.x << 16);
            acc.y += __builtin_bit_cast(float, pk.x & 0xffff0000u);
            acc.z += __builtin_bit_cast(float, pk.y << 16);
            acc.w += __builtin_bit_cast(float, pk.y & 0xffff0000u);
        }
    }
    float dv = dinv[node];
    acc.x *= dv; acc.y *= dv; acc.z *= dv; acc.w *= dv;
    if (BF16OUT) {
        uint2 pk;
        pk.x = (unsigned)f2bf(acc.x) | ((unsigned)f2bf(acc.y) << 16);
        pk.y = (unsigned)f2bf(acc.z) | ((unsigned)f2bf(acc.w) << 16);
        *(uint2*)(outh + (size_t)node * HD + l * 4) = pk;
    } else {
        *(float4*)(outf + (size_t)node * HD + l * 4) = acc;
    }
}

// ---------------------------------------------------------------------------
// pool + head fused: one block per graph (sorted batch -> contiguous ranges).
__global__ __launch_bounds__(512) void k_pool2(const unsigned short* __restrict__ acc2,
                                               const float* __restrict__ b2,
                                               const int* __restrict__ gstart,
                                               const float* __restrict__ fcw,
                                               const float* __restrict__ fcb,
                                               float* __restrict__ out) {
    int g = blockIdx.x;
    int tid = threadIdx.x;
    int c = tid & 127;              // channel
    int par = tid >> 7;             // row parity 0..3
    int s = gstart[g];
    int e = gstart[g + 1];
    float bias = b2[c];
    float sum = 0.0f;
    for (int i = s + par; i < e; i += 4)
        sum += fmaxf(bf2f(acc2[(size_t)i * HD + c]) + bias, 0.0f);

    __shared__ float ps[4][128];
    ps[par][c] = sum;
    __syncthreads();

    float a0 = 0.0f, a1 = 0.0f;
    if (tid < 128) {
        float p = (ps[0][c] + ps[1][c] + ps[2][c] + ps[3][c]) /
                  fmaxf((float)(e - s), 1.0f);
        a0 = p * fcw[c * 2 + 0];
        a1 = p * fcw[c * 2 + 1];
    }
#pragma unroll
    for (int off = 32; off; off >>= 1) {
        a0 += __shfl_down(a0, off, 64);
        a1 += __shfl_down(a1, off, 64);
    }
    __shared__ float r0[8], r1[8];
    if ((tid & 63) == 0) { r0[tid >> 6] = a0; r1[tid >> 6] = a1; }
    __syncthreads();
    if (tid == 0) {
        float l0 = r0[0] + r0[1] + fcb[0];
        float l1 = r1[0] + r1[1] + fcb[1];
        float m = fmaxf(l0, l1);
        float lse = m + logf(__expf(l0 - m) + __expf(l1 - m));
        out[g * 2 + 0] = l0 - lse;
        out[g * 2 + 1] = l1 - lse;
    }
}

// ---------------------------------------------------------------------------
extern "C" void kernel_launch(void* const* d_in, const int* in_sizes, int n_in,
                              void* d_out, int out_size, void* d_ws, size_t ws_size,
                              hipStream_t stream) {
    const float* x    = (const float*)d_in[0];
    const int*   ei   = (const int*)d_in[1];   // [2][NE]
    const int*   batch= (const int*)d_in[2];   // [NN] (sorted)
    const float* W1   = (const float*)d_in[3];
    const float* b1   = (const float*)d_in[4];
    const float* W2   = (const float*)d_in[5];
    const float* b2   = (const float*)d_in[6];
    const float* fcw  = (const float*)d_in[7];
    const float* fcb  = (const float*)d_in[8];
    float* out = (float*)d_out;

    // workspace layout (all offsets 8B-aligned)
    char* ws = (char*)d_ws;
    float* dinv    = (float*)ws;                        ws += 100352 * 4;
    unsigned short* bufA = (unsigned short*)ws;         ws += (size_t)NN * HD * 2;  // bf16 hs
    float* bufB    = (float*)ws;                        ws += (size_t)NN * HD * 4;  // fp32 agg1
    unsigned short* bufC = (unsigned short*)ws;         ws += (size_t)NN * HD * 2;  // bf16 agg2
    int*   row_ptr = (int*)ws;                          ws += 100352 * 4;
    int*   cnt_i   = (int*)ws;                          ws += 100352 * 4;
    int*   partial = (int*)ws;                          ws += 512 * 4;
    int*   gstart  = (int*)ws;                          ws += 520 * 4;
    unsigned short* W1t = (unsigned short*)ws;          ws += (size_t)128 * IND * 2;
    unsigned short* W2t = (unsigned short*)ws;          ws += (size_t)128 * HD * 2;
    int*   csr_src = (int*)ws;                          ws += (size_t)NE * 4;
    int*   cnt2    = (int*)ws;                          ws += (size_t)CHUNKS2 * NR * 4;
    int*   base2   = (int*)ws;                          ws += (size_t)CHUNKS2 * NR * 4;
    int2*  ebuf    = (int2*)ws;                         ws += (size_t)NE * 8;

    const int nblk = (NN + 255) / 256;           // 391
    const int mblk = (NN + 127) / 128;           // 782
    const int wblk = (NN * 32 + 255) / 256;      // 12500

    // prologue: zero | wprep | gbound
    k_p0<<<P0_Z + P0_W + P0_G, 256, 0, stream>>>(cnt_i, W1, W2, W1t, W2t, batch, gstart);

    // GEMM1 (unscaled) || degree count || per-chunk range histograms
    k_p1<<<GB1 + CB + CHUNKS2, 256, 0, stream>>>(x, W1t, bufA, ei, cnt_i, cnt2);

    // row_ptr scan + dinv
    k_scan1<<<nblk, 256, 0, stream>>>(cnt_i, row_ptr, partial);
    k_scan2<<<1, 512, 0, stream>>>(partial, nblk);
    k_scan3<<<nblk, 256, 0, stream>>>(row_ptr, cnt_i, partial, dinv);

    // F2 (bucket bases) || scale bufA by dinv
    k_p2<<<NR + P2_SC, 1024, 0, stream>>>(cnt2, row_ptr, base2, dinv, bufA);

    // F3: bucket edges by range; F4: scatter into CSR slots (LDS cursors)
    k_f3<<<CHUNKS2, 256, 0, stream>>>(ei, base2, ebuf);
    k_f4<<<NR, 1024, 0, stream>>>(row_ptr, ebuf, csr_src);

    // layer 1 aggregate -> bufB (fp32)
    k_gather<false><<<wblk, 256, 0, stream>>>(row_ptr, csr_src, dinv, bufA, bufB, nullptr);

    // layer 2: A = relu(bufB + b1) ; hs2 = dinv*(A@W2) -> bufA ; gather -> bufC
    k_gemm_mfma<HD, true, true><<<mblk, 256, 0, stream>>>(bufB, W2t, b1, dinv, bufA, NN);
    k_gather<true><<<wblk, 256, 0, stream>>>(row_ptr, csr_src, dinv, bufA, nullptr, bufC);

    // fused pool + head
    k_pool2<<<NG, 512, 0, stream>>>(bufC, b2, gstart, fcw, fcb, out);
}

// Round 9
// 283.051 us; speedup vs baseline: 20.9890x; 1.2172x over previous
//
#include <hip/hip_runtime.h>
#include <hip/hip_bf16.h>

// Problem constants
constexpr int NN = 100000;       // nodes
constexpr int NE = 1600000;      // edges
constexpr int NG = 512;          // graphs
constexpr int IND = 384;         // in dim
constexpr int HD  = 128;         // hidden dim

// CSR bucket-sort geometry (no global atomics anywhere)
constexpr int NR      = 128;             // node ranges
constexpr int RSPAN   = 782;             // nodes per range (128*782 >= NN)
constexpr int CHUNKS  = 800;             // edge chunks
constexpr int CHUNK_E = NE / CHUNKS;     // 2000 edges per chunk

typedef short bf16x8 __attribute__((ext_vector_type(8)));
typedef float f32x4  __attribute__((ext_vector_type(4)));

__device__ __forceinline__ unsigned short f2bf(float x) {
    unsigned int u = __builtin_bit_cast(unsigned int, x);
    u = (u + 0x7FFFu + ((u >> 16) & 1u)) >> 16;   // RNE
    return (unsigned short)u;
}
__device__ __forceinline__ float bf2f(unsigned short v) {
    return __builtin_bit_cast(float, (unsigned int)v << 16);
}

// ---------------------------------------------------------------------------
// MFMA bf16 GEMM: Cout[M x 128](bf16) = dinv[row] * (A(fp32->bf16) @ Wt^T)
// Wt is [128][K] bf16. If BR: A applies relu(a + bias) before conversion.
// 128x128 tile, BK=64, 4 waves each owning a 64x64 quadrant (4x4 16x16 frags).
template <int K, bool BR>
__global__ __launch_bounds__(256) void k_gemm_mfma(const float* __restrict__ A,
                                                   const unsigned short* __restrict__ Wt,
                                                   const float* __restrict__ bias,
                                                   const float* __restrict__ dinv,
                                                   unsigned short* __restrict__ Cout,
                                                   int M) {
    __shared__ unsigned short As[128][72];   // rows padded: stride 144B
    __shared__ unsigned short Bs[128][72];   // Bs[n][k]
    const int tid  = threadIdx.x;
    const int lane = tid & 63;
    const int wid  = tid >> 6;
    const int wm   = (wid & 1) * 64;
    const int wn   = (wid >> 1) * 64;
    const int m0   = blockIdx.x * 128;

    f32x4 acc[4][4];
#pragma unroll
    for (int i = 0; i < 4; ++i)
#pragma unroll
        for (int j = 0; j < 4; ++j) acc[i][j] = f32x4{0.f, 0.f, 0.f, 0.f};

    const int cg = tid & 15;      // A col group (4 fp32)
    const int rb = tid >> 4;      // A row base 0..15
    const int wrow = tid >> 1;    // Wt row 0..127
    const int wh   = tid & 1;     // Wt 32-col half

    for (int k0 = 0; k0 < K; k0 += 64) {
        // stage A tile (128 x 64 fp32 -> bf16)
#pragma unroll
        for (int p = 0; p < 8; ++p) {
            int r = rb + p * 16;
            int gr = m0 + r; if (gr > M - 1) gr = M - 1;
            float4 a = *(const float4*)(A + (size_t)gr * K + k0 + cg * 4);
            if (BR) {
                float4 bv = *(const float4*)(bias + k0 + cg * 4);
                a.x = fmaxf(a.x + bv.x, 0.0f);
                a.y = fmaxf(a.y + bv.y, 0.0f);
                a.z = fmaxf(a.z + bv.z, 0.0f);
                a.w = fmaxf(a.w + bv.w, 0.0f);
            }
            uint2 pk;
            pk.x = (unsigned)f2bf(a.x) | ((unsigned)f2bf(a.y) << 16);
            pk.y = (unsigned)f2bf(a.z) | ((unsigned)f2bf(a.w) << 16);
            *(uint2*)&As[r][cg * 4] = pk;
        }
        // stage Wt tile (128 rows x 64 bf16)
        {
            const uint4* src = (const uint4*)(Wt + (size_t)wrow * K + k0 + wh * 32);
#pragma unroll
            for (int q = 0; q < 4; ++q)
                *(uint4*)&Bs[wrow][wh * 32 + q * 8] = src[q];
        }
        __syncthreads();
#pragma unroll
        for (int ks = 0; ks < 2; ++ks) {
            bf16x8 af[4], bfr[4];
#pragma unroll
            for (int i = 0; i < 4; ++i)
                af[i] = *(const bf16x8*)&As[wm + i * 16 + (lane & 15)][ks * 32 + (lane >> 4) * 8];
#pragma unroll
            for (int i = 0; i < 4; ++i)
                bfr[i] = *(const bf16x8*)&Bs[wn + i * 16 + (lane & 15)][ks * 32 + (lane >> 4) * 8];
#pragma unroll
            for (int mi = 0; mi < 4; ++mi)
#pragma unroll
                for (int ni = 0; ni < 4; ++ni)
                    acc[mi][ni] = __builtin_amdgcn_mfma_f32_16x16x32_bf16(
                        af[mi], bfr[ni], acc[mi][ni], 0, 0, 0);
        }
        __syncthreads();
    }

    // epilogue: C/D frag layout col=lane&15, row=(lane>>4)*4+reg; emit bf16(dinv*acc)
#pragma unroll
    for (int mi = 0; mi < 4; ++mi) {
#pragma unroll
        for (int j = 0; j < 4; ++j) {
            int gr = m0 + wm + mi * 16 + (lane >> 4) * 4 + j;
            if (gr < M) {
                float dv = dinv[gr];
#pragma unroll
                for (int ni = 0; ni < 4; ++ni) {
                    int gc = wn + ni * 16 + (lane & 15);
                    Cout[(size_t)gr * HD + gc] = f2bf(acc[mi][ni][j] * dv);
                }
            }
        }
    }
}

// ---------------------------------------------------------------------------
// P0 fused prologue: weight transpose+convert | graph boundaries |
// F1: per-chunk range histogram (LDS atomics only)
constexpr int P0_W = 128 * (IND + HD) / 256; // 256
constexpr int P0_G = (NN + 255) / 256;       // 391
__global__ __launch_bounds__(256) void k_p0(const float* __restrict__ W1,
                                            const float* __restrict__ W2,
                                            unsigned short* __restrict__ W1t,
                                            unsigned short* __restrict__ W2t,
                                            const int* __restrict__ batch,
                                            int* __restrict__ gstart,
                                            const int* __restrict__ ei,
                                            int* __restrict__ cnt2) {
    __shared__ int hist[NR];
    int bid = blockIdx.x;
    int t = threadIdx.x;
    if (bid < P0_W) {
        int id = bid * 256 + t;
        if (id < 128 * IND) {
            int n = id / IND, k = id - n * IND;
            W1t[id] = f2bf(W1[(size_t)k * HD + n]);
        } else {
            int id2 = id - 128 * IND;
            int n = id2 >> 7, k = id2 & 127;
            W2t[id2] = f2bf(W2[(size_t)k * HD + n]);
        }
    } else if (bid < P0_W + P0_G) {
        int i = (bid - P0_W) * 256 + t;
        if (i < NN) {
            int b = batch[i];
            int prev = (i == 0) ? -1 : batch[i - 1];
            for (int g = prev + 1; g <= b; ++g) gstart[g] = i;
            if (i == NN - 1)
                for (int g = b + 1; g <= NG; ++g) gstart[g] = NN;
        }
    } else {
        int c = bid - P0_W - P0_G;
        if (t < NR) hist[t] = 0;
        __syncthreads();
        int e0 = c * CHUNK_E;
        for (int k = t; k < CHUNK_E; k += 256)
            atomicAdd(&hist[ei[NE + e0 + k] / RSPAN], 1);
        __syncthreads();
        if (t < NR) cnt2[c * NR + t] = hist[t];
    }
}

// F2a: per-range exclusive scan of cnt2 over chunks; totals -> T
__global__ __launch_bounds__(1024) void k_f2a(const int* __restrict__ cnt2,
                                              int* __restrict__ base2,
                                              int* __restrict__ T) {
    __shared__ int s[1024];
    int r = blockIdx.x, t = threadIdx.x;
    int v = (t < CHUNKS) ? cnt2[t * NR + r] : 0;
    s[t] = v;
    __syncthreads();
    for (int off = 1; off < 1024; off <<= 1) {
        int x = (t >= off) ? s[t - off] : 0;
        __syncthreads();
        s[t] += x;
        __syncthreads();
    }
    if (t < CHUNKS) base2[t * NR + r] = s[t] - v;
    if (t == 1023) T[r] = s[1023];
}

// F2b: exclusive scan of range totals -> rbase[NR+1]
__global__ __launch_bounds__(128) void k_f2b(const int* __restrict__ T,
                                             int* __restrict__ rbase) {
    __shared__ int s[NR];
    int t = threadIdx.x;
    int v = T[t];
    s[t] = v;
    __syncthreads();
    for (int off = 1; off < NR; off <<= 1) {
        int x = (t >= off) ? s[t - off] : 0;
        __syncthreads();
        s[t] += x;
        __syncthreads();
    }
    rbase[t] = s[t] - v;
    if (t == NR - 1) rbase[NR] = s[NR - 1];   // == NE
}

// F3: bucket edges by range at deterministic per-chunk offsets (LDS cursors)
__global__ __launch_bounds__(256) void k_f3(const int* __restrict__ ei,
                                            const int* __restrict__ base2,
                                            const int* __restrict__ rbase,
                                            int2* __restrict__ ebuf) {
    __shared__ int cur[NR];
    int c = blockIdx.x;
    int t = threadIdx.x;
    if (t < NR) cur[t] = rbase[t] + base2[c * NR + t];
    __syncthreads();
    int e0 = c * CHUNK_E;
    for (int k = t; k < CHUNK_E; k += 256) {
        int e = e0 + k;
        int sv = ei[e];
        int d = ei[NE + e];
        int pos = atomicAdd(&cur[d / RSPAN], 1);
        ebuf[pos] = make_int2(sv, d);
    }
}

// F4: one block per range; per-node degree (LDS), LDS scan -> row_ptr + dinv,
// then scatter bucketed edges into exact CSR slots via LDS cursors.
// Zero global atomics; all touched spans are range-local.
__global__ __launch_bounds__(1024) void k_f4(const int2* __restrict__ ebuf,
                                             const int* __restrict__ rbase,
                                             int* __restrict__ row_ptr,
                                             float* __restrict__ dinv,
                                             int* __restrict__ csr_src) {
    __shared__ int cnt[RSPAN];
    __shared__ int s[1024];
    int r = blockIdx.x, t = threadIdx.x;
    int lo = r * RSPAN;
    int hi = min(lo + RSPAN, NN);
    int span = hi - lo;
    if (t < span) cnt[t] = 0;
    __syncthreads();
    int es = rbase[r], ee = rbase[r + 1];
    for (int e = es + t; e < ee; e += 1024)
        atomicAdd(&cnt[ebuf[e].y - lo], 1);
    __syncthreads();
    int v = (t < span) ? cnt[t] : 0;
    s[t] = v;
    __syncthreads();
    for (int off = 1; off < 1024; off <<= 1) {
        int x = (t >= off) ? s[t - off] : 0;
        __syncthreads();
        s[t] += x;
        __syncthreads();
    }
    int base = es + s[t] - v;      // exclusive CSR start for node lo+t
    if (t < span) {
        row_ptr[lo + t] = base;
        dinv[lo + t] = rsqrtf((float)v + 1.0f);
    }
    __syncthreads();
    if (t < span) cnt[t] = base;   // reuse as cursors
    __syncthreads();
    for (int e = es + t; e < ee; e += 1024) {
        int2 ed = ebuf[e];
        int pos = atomicAdd(&cnt[ed.y - lo], 1);
        csr_src[pos] = ed.x;
    }
    if (r == 0 && t == 0) row_ptr[NN] = NE;
}

// ---------------------------------------------------------------------------
// gather: out[n] = dinv[n] * (hs[n] + sum_{e in CSR row n} hs[src[e]])
// hs is bf16 [NN][128] pre-scaled by dinv; 32 lanes/node, 4 ch (8B) per lane.
template <bool BF16OUT>
__global__ __launch_bounds__(256) void k_gather(const int* __restrict__ row_ptr,
                                                const int* __restrict__ csr_src,
                                                const float* __restrict__ dinv,
                                                const unsigned short* __restrict__ hs,
                                                float* __restrict__ outf,
                                                unsigned short* __restrict__ outh) {
    int gid = blockIdx.x * 256 + threadIdx.x;
    int node = gid >> 5;
    int l = threadIdx.x & 31;
    if (node >= NN) return;
    int start = row_ptr[node];
    int end   = row_ptr[node + 1];
    uint2 hp = *(const uint2*)(hs + (size_t)node * HD + l * 4);
    float4 acc;
    acc.x = __builtin_bit_cast(float, hp.x << 16);
    acc.y = __builtin_bit_cast(float, hp.x & 0xffff0000u);
    acc.z = __builtin_bit_cast(float, hp.y << 16);
    acc.w = __builtin_bit_cast(float, hp.y & 0xffff0000u);
    for (int eb = start; eb < end; eb += 32) {
        int idx = eb + l;
        int src = 0;
        if (idx < end) src = csr_src[idx];
        int n = min(32, end - eb);
#pragma unroll 8
        for (int j = 0; j < n; ++j) {
            int s = __shfl(src, j, 32);
            uint2 pk = *(const uint2*)(hs + (size_t)s * HD + l * 4);
            acc.x += __builtin_bit_cast(float, pk.x << 16);
            acc.y += __builtin_bit_cast(float, pk.x & 0xffff0000u);
            acc.z += __builtin_bit_cast(float, pk.y << 16);
            acc.w += __builtin_bit_cast(float, pk.y & 0xffff0000u);
        }
    }
    float dv = dinv[node];
    acc.x *= dv; acc.y *= dv; acc.z *= dv; acc.w *= dv;
    if (BF16OUT) {
        uint2 pk;
        pk.x = (unsigned)f2bf(acc.x) | ((unsigned)f2bf(acc.y) << 16);
        pk.y = (unsigned)f2bf(acc.z) | ((unsigned)f2bf(acc.w) << 16);
        *(uint2*)(outh + (size_t)node * HD + l * 4) = pk;
    } else {
        *(float4*)(outf + (size_t)node * HD + l * 4) = acc;
    }
}

// ---------------------------------------------------------------------------
// pool + head fused: one block per graph (sorted batch -> contiguous ranges).
__global__ __launch_bounds__(512) void k_pool2(const unsigned short* __restrict__ acc2,
                                               const float* __restrict__ b2,
                                               const int* __restrict__ gstart,
                                               const float* __restrict__ fcw,
                                               const float* __restrict__ fcb,
                                               float* __restrict__ out) {
    int g = blockIdx.x;
    int tid = threadIdx.x;
    int c = tid & 127;              // channel
    int par = tid >> 7;             // row parity 0..3
    int s = gstart[g];
    int e = gstart[g + 1];
    float bias = b2[c];
    float sum = 0.0f;
    for (int i = s + par; i < e; i += 4)
        sum += fmaxf(bf2f(acc2[(size_t)i * HD + c]) + bias, 0.0f);

    __shared__ float ps[4][128];
    ps[par][c] = sum;
    __syncthreads();

    float a0 = 0.0f, a1 = 0.0f;
    if (tid < 128) {
        float p = (ps[0][c] + ps[1][c] + ps[2][c] + ps[3][c]) /
                  fmaxf((float)(e - s), 1.0f);
        a0 = p * fcw[c * 2 + 0];
        a1 = p * fcw[c * 2 + 1];
    }
#pragma unroll
    for (int off = 32; off; off >>= 1) {
        a0 += __shfl_down(a0, off, 64);
        a1 += __shfl_down(a1, off, 64);
    }
    __shared__ float r0[8], r1[8];
    if ((tid & 63) == 0) { r0[tid >> 6] = a0; r1[tid >> 6] = a1; }
    __syncthreads();
    if (tid == 0) {
        float l0 = r0[0] + r0[1] + fcb[0];
        float l1 = r1[0] + r1[1] + fcb[1];
        float m = fmaxf(l0, l1);
        float lse = m + logf(__expf(l0 - m) + __expf(l1 - m));
        out[g * 2 + 0] = l0 - lse;
        out[g * 2 + 1] = l1 - lse;
    }
}

// ---------------------------------------------------------------------------
extern "C" void kernel_launch(void* const* d_in, const int* in_sizes, int n_in,
                              void* d_out, int out_size, void* d_ws, size_t ws_size,
                              hipStream_t stream) {
    const float* x    = (const float*)d_in[0];
    const int*   ei   = (const int*)d_in[1];   // [2][NE]
    const int*   batch= (const int*)d_in[2];   // [NN] (sorted)
    const float* W1   = (const float*)d_in[3];
    const float* b1   = (const float*)d_in[4];
    const float* W2   = (const float*)d_in[5];
    const float* b2   = (const float*)d_in[6];
    const float* fcw  = (const float*)d_in[7];
    const float* fcb  = (const float*)d_in[8];
    float* out = (float*)d_out;

    // workspace layout (all offsets 8B-aligned)
    char* ws = (char*)d_ws;
    float* dinv    = (float*)ws;                        ws += 100352 * 4;
    unsigned short* bufA = (unsigned short*)ws;         ws += (size_t)NN * HD * 2;  // bf16 hs
    float* bufB    = (float*)ws;                        ws += (size_t)NN * HD * 4;  // fp32 agg1
    unsigned short* bufC = (unsigned short*)ws;         ws += (size_t)NN * HD * 2;  // bf16 agg2
    int*   row_ptr = (int*)ws;                          ws += 100352 * 4;
    int*   gstart  = (int*)ws;                          ws += 520 * 4;
    unsigned short* W1t = (unsigned short*)ws;          ws += (size_t)128 * IND * 2;
    unsigned short* W2t = (unsigned short*)ws;          ws += (size_t)128 * HD * 2;
    int*   csr_src = (int*)ws;                          ws += (size_t)NE * 4;
    int*   cnt2    = (int*)ws;                          ws += (size_t)CHUNKS * NR * 4;
    int*   base2   = (int*)ws;                          ws += (size_t)CHUNKS * NR * 4;
    int*   T       = (int*)ws;                          ws += NR * 4;
    int*   rbase   = (int*)ws;                          ws += (NR + 8) * 4;
    int2*  ebuf    = (int2*)ws;                         ws += (size_t)NE * 8;

    const int mblk = (NN + 127) / 128;           // 782
    const int wblk = (NN * 32 + 255) / 256;      // 12500

    // prologue: wprep | gbound | F1 per-chunk range histograms (LDS only)
    k_p0<<<P0_W + P0_G + CHUNKS, 256, 0, stream>>>(W1, W2, W1t, W2t, batch, gstart, ei, cnt2);

    // F2: deterministic bucket bases (exclusive scans)
    k_f2a<<<NR, 1024, 0, stream>>>(cnt2, base2, T);
    k_f2b<<<1, NR, 0, stream>>>(T, rbase);

    // F3: bucket (src,dst) by range; F4: per-range degree+scan+scatter
    k_f3<<<CHUNKS, 256, 0, stream>>>(ei, base2, rbase, ebuf);
    k_f4<<<NR, 1024, 0, stream>>>(ebuf, rbase, row_ptr, dinv, csr_src);

    // layer 1: hs1 = dinv*(x@W1) -> bufA (bf16) ; gather -> bufB (fp32)
    k_gemm_mfma<IND, false><<<mblk, 256, 0, stream>>>(x, W1t, nullptr, dinv, bufA, NN);
    k_gather<false><<<wblk, 256, 0, stream>>>(row_ptr, csr_src, dinv, bufA, bufB, nullptr);

    // layer 2: A = relu(bufB + b1) ; hs2 = dinv*(A@W2) -> bufA ; gather -> bufC
    k_gemm_mfma<HD, true><<<mblk, 256, 0, stream>>>(bufB, W2t, b1, dinv, bufA, NN);
    k_gather<true><<<wblk, 256, 0, stream>>>(row_ptr, csr_src, dinv, bufA, nullptr, bufC);

    // fused pool + head
    k_pool2<<<NG, 512, 0, stream>>>(bufC, b2, gstart, fcw, fcb, out);
}

// Round 10
// 265.502 us; speedup vs baseline: 22.3763x; 1.0661x over previous
//
#include <hip/hip_runtime.h>
#include <hip/hip_bf16.h>

// Problem constants
constexpr int NN = 100000;       // nodes
constexpr int NE = 1600000;      // edges
constexpr int NG = 512;          // graphs
constexpr int IND = 384;         // in dim
constexpr int HD  = 128;         // hidden dim

// CSR bucket-sort geometry (no global atomics anywhere)
constexpr int NR      = 128;             // node ranges
constexpr int RSPAN   = 782;             // nodes per range (128*782 >= NN)
constexpr int CHUNKS  = 800;             // edge chunks
constexpr int CHUNK_E = NE / CHUNKS;     // 2000 edges per chunk

typedef short bf16x8 __attribute__((ext_vector_type(8)));
typedef float f32x4  __attribute__((ext_vector_type(4)));

__device__ __forceinline__ unsigned short f2bf(float x) {
    unsigned int u = __builtin_bit_cast(unsigned int, x);
    u = (u + 0x7FFFu + ((u >> 16) & 1u)) >> 16;   // RNE
    return (unsigned short)u;
}
__device__ __forceinline__ float bf2f(unsigned short v) {
    return __builtin_bit_cast(float, (unsigned int)v << 16);
}

// ---------------------------------------------------------------------------
// GEMM body: Cout[M x 128](bf16) = [dinv[row] *] (A(fp32->bf16) @ Wt^T)
// Wt is [128][K] bf16. If BR: A applies relu(a + bias) before conversion.
// 128x128 tile, BK=64, 4 waves each owning a 64x64 quadrant (4x4 16x16 frags).
template <int K, bool BR, bool SC>
__device__ __forceinline__ void gemm_body(int bid,
                                          const float* __restrict__ A,
                                          const unsigned short* __restrict__ Wt,
                                          const float* __restrict__ bias,
                                          const float* __restrict__ dinv,
                                          unsigned short* __restrict__ Cout,
                                          int M,
                                          unsigned short (*As)[72],
                                          unsigned short (*Bs)[72]) {
    const int tid  = threadIdx.x;
    const int lane = tid & 63;
    const int wid  = tid >> 6;
    const int wm   = (wid & 1) * 64;
    const int wn   = (wid >> 1) * 64;
    const int m0   = bid * 128;

    f32x4 acc[4][4];
#pragma unroll
    for (int i = 0; i < 4; ++i)
#pragma unroll
        for (int j = 0; j < 4; ++j) acc[i][j] = f32x4{0.f, 0.f, 0.f, 0.f};

    const int cg = tid & 15;      // A col group (4 fp32)
    const int rb = tid >> 4;      // A row base 0..15
    const int wrow = tid >> 1;    // Wt row 0..127
    const int wh   = tid & 1;     // Wt 32-col half

    for (int k0 = 0; k0 < K; k0 += 64) {
#pragma unroll
        for (int p = 0; p < 8; ++p) {
            int r = rb + p * 16;
            int gr = m0 + r; if (gr > M - 1) gr = M - 1;
            float4 a = *(const float4*)(A + (size_t)gr * K + k0 + cg * 4);
            if (BR) {
                float4 bv = *(const float4*)(bias + k0 + cg * 4);
                a.x = fmaxf(a.x + bv.x, 0.0f);
                a.y = fmaxf(a.y + bv.y, 0.0f);
                a.z = fmaxf(a.z + bv.z, 0.0f);
                a.w = fmaxf(a.w + bv.w, 0.0f);
            }
            uint2 pk;
            pk.x = (unsigned)f2bf(a.x) | ((unsigned)f2bf(a.y) << 16);
            pk.y = (unsigned)f2bf(a.z) | ((unsigned)f2bf(a.w) << 16);
            *(uint2*)&As[r][cg * 4] = pk;
        }
        {
            const uint4* src = (const uint4*)(Wt + (size_t)wrow * K + k0 + wh * 32);
#pragma unroll
            for (int q = 0; q < 4; ++q)
                *(uint4*)&Bs[wrow][wh * 32 + q * 8] = src[q];
        }
        __syncthreads();
#pragma unroll
        for (int ks = 0; ks < 2; ++ks) {
            bf16x8 af[4], bfr[4];
#pragma unroll
            for (int i = 0; i < 4; ++i)
                af[i] = *(const bf16x8*)&As[wm + i * 16 + (lane & 15)][ks * 32 + (lane >> 4) * 8];
#pragma unroll
            for (int i = 0; i < 4; ++i)
                bfr[i] = *(const bf16x8*)&Bs[wn + i * 16 + (lane & 15)][ks * 32 + (lane >> 4) * 8];
#pragma unroll
            for (int mi = 0; mi < 4; ++mi)
#pragma unroll
                for (int ni = 0; ni < 4; ++ni)
                    acc[mi][ni] = __builtin_amdgcn_mfma_f32_16x16x32_bf16(
                        af[mi], bfr[ni], acc[mi][ni], 0, 0, 0);
        }
        __syncthreads();
    }

    // epilogue: C/D frag layout col=lane&15, row=(lane>>4)*4+reg
#pragma unroll
    for (int mi = 0; mi < 4; ++mi) {
#pragma unroll
        for (int j = 0; j < 4; ++j) {
            int gr = m0 + wm + mi * 16 + (lane >> 4) * 4 + j;
            if (gr < M) {
                float dv = SC ? dinv[gr] : 1.0f;
#pragma unroll
                for (int ni = 0; ni < 4; ++ni) {
                    int gc = wn + ni * 16 + (lane & 15);
                    Cout[(size_t)gr * HD + gc] = f2bf(acc[mi][ni][j] * dv);
                }
            }
        }
    }
}

template <int K, bool BR, bool SC>
__global__ __launch_bounds__(256) void k_gemm_mfma(const float* __restrict__ A,
                                                   const unsigned short* __restrict__ Wt,
                                                   const float* __restrict__ bias,
                                                   const float* __restrict__ dinv,
                                                   unsigned short* __restrict__ Cout,
                                                   int M) {
    __shared__ unsigned short As[128][72];
    __shared__ unsigned short Bs[128][72];
    gemm_body<K, BR, SC>(blockIdx.x, A, Wt, bias, dinv, Cout, M, As, Bs);
}

// ---------------------------------------------------------------------------
// P0 fused prologue: weight transpose+convert | graph boundaries |
// F1: per-chunk range histogram (LDS atomics only)
constexpr int P0_W = 128 * (IND + HD) / 256; // 256
constexpr int P0_G = (NN + 255) / 256;       // 391
__global__ __launch_bounds__(256) void k_p0(const float* __restrict__ W1,
                                            const float* __restrict__ W2,
                                            unsigned short* __restrict__ W1t,
                                            unsigned short* __restrict__ W2t,
                                            const int* __restrict__ batch,
                                            int* __restrict__ gstart,
                                            const int* __restrict__ ei,
                                            int* __restrict__ cnt2) {
    __shared__ int hist[NR];
    int bid = blockIdx.x;
    int t = threadIdx.x;
    if (bid < P0_W) {
        int id = bid * 256 + t;
        if (id < 128 * IND) {
            int n = id / IND, k = id - n * IND;
            W1t[id] = f2bf(W1[(size_t)k * HD + n]);
        } else {
            int id2 = id - 128 * IND;
            int n = id2 >> 7, k = id2 & 127;
            W2t[id2] = f2bf(W2[(size_t)k * HD + n]);
        }
    } else if (bid < P0_W + P0_G) {
        int i = (bid - P0_W) * 256 + t;
        if (i < NN) {
            int b = batch[i];
            int prev = (i == 0) ? -1 : batch[i - 1];
            for (int g = prev + 1; g <= b; ++g) gstart[g] = i;
            if (i == NN - 1)
                for (int g = b + 1; g <= NG; ++g) gstart[g] = NN;
        }
    } else {
        int c = bid - P0_W - P0_G;
        if (t < NR) hist[t] = 0;
        __syncthreads();
        int e0 = c * CHUNK_E;
        for (int k = t; k < CHUNK_E; k += 256)
            atomicAdd(&hist[ei[NE + e0 + k] / RSPAN], 1);
        __syncthreads();
        if (t < NR) cnt2[c * NR + t] = hist[t];
    }
}

// F2: per-range exclusive scan of cnt2 over chunks; totals -> T
__global__ __launch_bounds__(1024) void k_f2a(const int* __restrict__ cnt2,
                                              int* __restrict__ base2,
                                              int* __restrict__ T) {
    __shared__ int s[1024];
    int r = blockIdx.x, t = threadIdx.x;
    int v = (t < CHUNKS) ? cnt2[t * NR + r] : 0;
    s[t] = v;
    __syncthreads();
    for (int off = 1; off < 1024; off <<= 1) {
        int x = (t >= off) ? s[t - off] : 0;
        __syncthreads();
        s[t] += x;
        __syncthreads();
    }
    if (t < CHUNKS) base2[t * NR + r] = s[t] - v;
    if (t == 1023) T[r] = s[1023];
}

// ---------------------------------------------------------------------------
// F3 + GEMM1 fused. Blocks [0, CHUNKS): bucket edges by range at
// deterministic offsets (in-block scan of T gives range bases; LDS cursors).
// Packed entry: (local_dst << 17) | src  (src < 2^17, local_dst < 782).
// Blocks [CHUNKS, CHUNKS+GB1): GEMM1 h1 = x@W1 (unscaled bf16) -> bufA.
constexpr int GB1 = (NN + 127) / 128;    // 782
__global__ __launch_bounds__(256) void k_f3g(const int* __restrict__ ei,
                                             const int* __restrict__ base2,
                                             const int* __restrict__ T,
                                             int* __restrict__ ebuf,
                                             const float* __restrict__ x,
                                             const unsigned short* __restrict__ W1t,
                                             unsigned short* __restrict__ bufA) {
    __shared__ unsigned short As[128][72];
    __shared__ unsigned short Bs[128][72];
    __shared__ int cur[NR];
    __shared__ int sT[NR];
    int bid = blockIdx.x;
    int t = threadIdx.x;
    if (bid >= CHUNKS) {
        gemm_body<IND, false, false>(bid - CHUNKS, x, W1t, nullptr, nullptr,
                                     bufA, NN, As, Bs);
        return;
    }
    int c = bid;
    int Tv = (t < NR) ? T[t] : 0;
    if (t < NR) sT[t] = Tv;
    __syncthreads();
    for (int off = 1; off < NR; off <<= 1) {
        int xv = (t >= off && t < NR) ? sT[t - off] : 0;
        __syncthreads();
        if (t < NR) sT[t] += xv;
        __syncthreads();
    }
    if (t < NR) cur[t] = (sT[t] - Tv) + base2[c * NR + t];
    __syncthreads();
    int e0 = c * CHUNK_E;
    for (int k = t; k < CHUNK_E; k += 256) {
        int e = e0 + k;
        int sv = ei[e];
        int d = ei[NE + e];
        int r = d / RSPAN;
        int pos = atomicAdd(&cur[r], 1);
        ebuf[pos] = ((d - r * RSPAN) << 17) | sv;
    }
}

// F4: one block per range; per-node degree (LDS), LDS scan -> row_ptr + dinv,
// then scatter bucketed edges into exact CSR slots via LDS cursors.
__global__ __launch_bounds__(1024) void k_f4(const int* __restrict__ ebuf,
                                             const int* __restrict__ T,
                                             int* __restrict__ row_ptr,
                                             float* __restrict__ dinv,
                                             int* __restrict__ csr_src) {
    __shared__ int cnt[RSPAN];
    __shared__ int s[1024];
    __shared__ int sT[NR];
    int r = blockIdx.x, t = threadIdx.x;
    // in-block inclusive scan of T -> range bounds
    if (t < NR) sT[t] = T[t];
    __syncthreads();
    for (int off = 1; off < NR; off <<= 1) {
        int xv = (t >= off && t < NR) ? sT[t - off] : 0;
        __syncthreads();
        if (t < NR) sT[t] += xv;
        __syncthreads();
    }
    int es = (r == 0) ? 0 : sT[r - 1];
    int ee = sT[r];
    int lo = r * RSPAN;
    int hi = min(lo + RSPAN, NN);
    int span = hi - lo;
    if (t < span) cnt[t] = 0;
    __syncthreads();
    for (int e = es + t; e < ee; e += 1024)
        atomicAdd(&cnt[ebuf[e] >> 17], 1);
    __syncthreads();
    int v = (t < span) ? cnt[t] : 0;
    s[t] = v;
    __syncthreads();
    for (int off = 1; off < 1024; off <<= 1) {
        int xv = (t >= off) ? s[t - off] : 0;
        __syncthreads();
        s[t] += xv;
        __syncthreads();
    }
    int base = es + s[t] - v;
    if (t < span) {
        row_ptr[lo + t] = base;
        dinv[lo + t] = rsqrtf((float)v + 1.0f);
    }
    __syncthreads();
    if (t < span) cnt[t] = base;   // reuse as cursors
    __syncthreads();
    for (int e = es + t; e < ee; e += 1024) {
        int ev = ebuf[e];
        int pos = atomicAdd(&cnt[ev >> 17], 1);
        csr_src[pos] = ev & 0x1FFFF;
    }
    if (r == 0 && t == 0) row_ptr[NN] = NE;
}

// ---------------------------------------------------------------------------
// gather. NORM=true (layer 1, hs unscaled h1):
//   out[n] = dinv[n] * (dinv[n]*h[n] + sum_e dinv[src]*h[src])
// NORM=false (layer 2, hs pre-scaled by dinv):
//   out[n] = dinv[n] * (hs[n] + sum_e hs[src])
// 32 lanes/node, 4 ch (8B) per lane; fp32 accumulate.
template <bool NORM, bool BF16OUT>
__global__ __launch_bounds__(256) void k_gather(const int* __restrict__ row_ptr,
                                                const int* __restrict__ csr_src,
                                                const float* __restrict__ dinv,
                                                const unsigned short* __restrict__ hs,
                                                float* __restrict__ outf,
                                                unsigned short* __restrict__ outh) {
    int gid = blockIdx.x * 256 + threadIdx.x;
    int node = gid >> 5;
    int l = threadIdx.x & 31;
    if (node >= NN) return;
    int start = row_ptr[node];
    int end   = row_ptr[node + 1];
    float dv = dinv[node];
    uint2 hp = *(const uint2*)(hs + (size_t)node * HD + l * 4);
    float sf = NORM ? dv : 1.0f;
    float4 acc;
    acc.x = sf * __builtin_bit_cast(float, hp.x << 16);
    acc.y = sf * __builtin_bit_cast(float, hp.x & 0xffff0000u);
    acc.z = sf * __builtin_bit_cast(float, hp.y << 16);
    acc.w = sf * __builtin_bit_cast(float, hp.y & 0xffff0000u);
    for (int eb = start; eb < end; eb += 32) {
        int idx = eb + l;
        int src = 0;
        float w = 0.0f;
        if (idx < end) {
            src = csr_src[idx];
            if (NORM) w = dinv[src];
        }
        int n = min(32, end - eb);
#pragma unroll 8
        for (int j = 0; j < n; ++j) {
            int s = __shfl(src, j, 32);
            uint2 pk = *(const uint2*)(hs + (size_t)s * HD + l * 4);
            if (NORM) {
                float ww = __shfl(w, j, 32);
                acc.x = fmaf(ww, __builtin_bit_cast(float, pk.x << 16), acc.x);
                acc.y = fmaf(ww, __builtin_bit_cast(float, pk.x & 0xffff0000u), acc.y);
                acc.z = fmaf(ww, __builtin_bit_cast(float, pk.y << 16), acc.z);
                acc.w = fmaf(ww, __builtin_bit_cast(float, pk.y & 0xffff0000u), acc.w);
            } else {
                acc.x += __builtin_bit_cast(float, pk.x << 16);
                acc.y += __builtin_bit_cast(float, pk.x & 0xffff0000u);
                acc.z += __builtin_bit_cast(float, pk.y << 16);
                acc.w += __builtin_bit_cast(float, pk.y & 0xffff0000u);
            }
        }
    }
    acc.x *= dv; acc.y *= dv; acc.z *= dv; acc.w *= dv;
    if (BF16OUT) {
        uint2 pk;
        pk.x = (unsigned)f2bf(acc.x) | ((unsigned)f2bf(acc.y) << 16);
        pk.y = (unsigned)f2bf(acc.z) | ((unsigned)f2bf(acc.w) << 16);
        *(uint2*)(outh + (size_t)node * HD + l * 4) = pk;
    } else {
        *(float4*)(outf + (size_t)node * HD + l * 4) = acc;
    }
}

// ---------------------------------------------------------------------------
// pool + head fused: one block per graph (sorted batch -> contiguous ranges).
__global__ __launch_bounds__(512) void k_pool2(const unsigned short* __restrict__ acc2,
                                               const float* __restrict__ b2,
                                               const int* __restrict__ gstart,
                                               const float* __restrict__ fcw,
                                               const float* __restrict__ fcb,
                                               float* __restrict__ out) {
    int g = blockIdx.x;
    int tid = threadIdx.x;
    int c = tid & 127;              // channel
    int par = tid >> 7;             // row parity 0..3
    int s = gstart[g];
    int e = gstart[g + 1];
    float bias = b2[c];
    float sum = 0.0f;
    for (int i = s + par; i < e; i += 4)
        sum += fmaxf(bf2f(acc2[(size_t)i * HD + c]) + bias, 0.0f);

    __shared__ float ps[4][128];
    ps[par][c] = sum;
    __syncthreads();

    float a0 = 0.0f, a1 = 0.0f;
    if (tid < 128) {
        float p = (ps[0][c] + ps[1][c] + ps[2][c] + ps[3][c]) /
                  fmaxf((float)(e - s), 1.0f);
        a0 = p * fcw[c * 2 + 0];
        a1 = p * fcw[c * 2 + 1];
    }
#pragma unroll
    for (int off = 32; off; off >>= 1) {
        a0 += __shfl_down(a0, off, 64);
        a1 += __shfl_down(a1, off, 64);
    }
    __shared__ float r0[8], r1[8];
    if ((tid & 63) == 0) { r0[tid >> 6] = a0; r1[tid >> 6] = a1; }
    __syncthreads();
    if (tid == 0) {
        float l0 = r0[0] + r0[1] + fcb[0];
        float l1 = r1[0] + r1[1] + fcb[1];
        float m = fmaxf(l0, l1);
        float lse = m + logf(__expf(l0 - m) + __expf(l1 - m));
        out[g * 2 + 0] = l0 - lse;
        out[g * 2 + 1] = l1 - lse;
    }
}

// ---------------------------------------------------------------------------
extern "C" void kernel_launch(void* const* d_in, const int* in_sizes, int n_in,
                              void* d_out, int out_size, void* d_ws, size_t ws_size,
                              hipStream_t stream) {
    const float* x    = (const float*)d_in[0];
    const int*   ei   = (const int*)d_in[1];   // [2][NE]
    const int*   batch= (const int*)d_in[2];   // [NN] (sorted)
    const float* W1   = (const float*)d_in[3];
    const float* b1   = (const float*)d_in[4];
    const float* W2   = (const float*)d_in[5];
    const float* b2   = (const float*)d_in[6];
    const float* fcw  = (const float*)d_in[7];
    const float* fcb  = (const float*)d_in[8];
    float* out = (float*)d_out;

    // workspace layout (all offsets 8B-aligned)
    char* ws = (char*)d_ws;
    float* dinv    = (float*)ws;                        ws += 100352 * 4;
    unsigned short* bufA = (unsigned short*)ws;         ws += (size_t)NN * HD * 2;  // bf16 h/hs
    float* bufB    = (float*)ws;                        ws += (size_t)NN * HD * 4;  // fp32 agg1
    unsigned short* bufC = (unsigned short*)ws;         ws += (size_t)NN * HD * 2;  // bf16 agg2
    int*   row_ptr = (int*)ws;                          ws += 100352 * 4;
    int*   gstart  = (int*)ws;                          ws += 520 * 4;
    unsigned short* W1t = (unsigned short*)ws;          ws += (size_t)128 * IND * 2;
    unsigned short* W2t = (unsigned short*)ws;          ws += (size_t)128 * HD * 2;
    int*   csr_src = (int*)ws;                          ws += (size_t)NE * 4;
    int*   cnt2    = (int*)ws;                          ws += (size_t)CHUNKS * NR * 4;
    int*   base2   = (int*)ws;                          ws += (size_t)CHUNKS * NR * 4;
    int*   T       = (int*)ws;                          ws += NR * 4;
    int*   ebuf    = (int*)ws;                          ws += (size_t)NE * 4;

    const int mblk = (NN + 127) / 128;           // 782
    const int wblk = (NN * 32 + 255) / 256;      // 12500

    // prologue: wprep | gbound | F1 per-chunk range histograms (LDS only)
    k_p0<<<P0_W + P0_G + CHUNKS, 256, 0, stream>>>(W1, W2, W1t, W2t, batch, gstart, ei, cnt2);

    // F2: deterministic bucket bases
    k_f2a<<<NR, 1024, 0, stream>>>(cnt2, base2, T);

    // F3 (bucket packed edges) || GEMM1 (h1 unscaled -> bufA)
    k_f3g<<<CHUNKS + GB1, 256, 0, stream>>>(ei, base2, T, ebuf, x, W1t, bufA);

    // F4: per-range degree+scan -> row_ptr,dinv; scatter -> csr_src
    k_f4<<<NR, 1024, 0, stream>>>(ebuf, T, row_ptr, dinv, csr_src);

    // layer 1 aggregate (per-edge dinv[src] weights) -> bufB (fp32)
    k_gather<true, false><<<wblk, 256, 0, stream>>>(row_ptr, csr_src, dinv, bufA, bufB, nullptr);

    // layer 2: A = relu(bufB + b1) ; hs2 = dinv*(A@W2) -> bufA ; gather -> bufC
    k_gemm_mfma<HD, true, true><<<mblk, 256, 0, stream>>>(bufB, W2t, b1, dinv, bufA, NN);
    k_gather<false, true><<<wblk, 256, 0, stream>>>(row_ptr, csr_src, dinv, bufA, nullptr, bufC);

    // fused pool + head
    k_pool2<<<NG, 512, 0, stream>>>(bufC, b2, gstart, fcw, fcb, out);
}